// Round 9
// baseline (196.021 us; speedup 1.0000x reference)
//
#include <hip/hip_runtime.h>

// (B,N,H,NB,NCT) = (8,4096,1024,128,33), H/2 = 512
#define NTOK 4096
#define HDIM 1024
#define HHALF 512
#define NBLK 128
#define CAP 256

typedef __attribute__((ext_vector_type(8))) short short8;
typedef __attribute__((ext_vector_type(4))) float f32x4;
typedef short bf16s;

__device__ __forceinline__ short f2bf(float f) {
    unsigned u = __builtin_bit_cast(unsigned, f);
    u = (u + 0x7fffu + ((u >> 16) & 1u)) >> 16;   // RNE
    return (short)u;
}
__device__ __forceinline__ float fast_tanh(float v) {
    float e = __expf(2.0f * v);
    return 1.0f - 2.0f / (e + 1.0f);
}
__device__ __forceinline__ void gload_lds16(const void* g, void* l) {
    __builtin_amdgcn_global_load_lds(
        (const __attribute__((address_space(1))) unsigned int*)g,
        (__attribute__((address_space(3))) unsigned int*)l, 16, 0, 0);
}

// ---------------------------------------------------------------------------
// Tiled transpose+convert for both weights in one launch.
// ---------------------------------------------------------------------------
__global__ void k_tcvt2(const float* __restrict__ W1, const float* __restrict__ Wp,
                        bf16s* __restrict__ w1t, bf16s* __restrict__ wpt) {
    __shared__ float tile[64][65];
    const int by = blockIdx.y;
    const float* in = (by < 8) ? W1 : Wp;
    bf16s* out = (by < 8) ? w1t : wpt;
    const int Nc = (by < 8) ? HHALF : HDIM;
    const int n0 = ((by < 8) ? by : (by - 8)) * 64;
    const int k0 = blockIdx.x * 64;
    const int tx = threadIdx.x & 63, ty = threadIdx.x >> 6;
    #pragma unroll
    for (int i = 0; i < 16; ++i) {
        int r = ty + i * 4;
        tile[r][tx] = in[(size_t)(k0 + r) * Nc + n0 + tx];
    }
    __syncthreads();
    #pragma unroll
    for (int i = 0; i < 16; ++i) {
        int r = ty + i * 4;
        out[(size_t)(n0 + r) * 1024 + k0 + tx] = f2bf(tile[tx][r]);
    }
}

// ---------------------------------------------------------------------------
// Gate GEMM, "register-B" structure:
//  - A: f32 x -> regs (1-iter prefetch) -> f2bf -> tri-buffered LDS (pad-36),
//    ONE raw barrier per iter (stage t+2 and compute t use disjoint buffers).
//  - B: direct global->register loads from L2-hot w1t, reg-double-buffered.
//    No LDS for B, no global_load_lds, no hand vmcnt: every vmem consumer's
//    wait is compiler-auto and >= 1 iteration old.
//  - col0==0 workgroups side-write bf16 xb for the pooling kernel.
// 128x128 tile, BK=32, 4 waves (2x2), acc[4][4]. LDS 28KB, 3 wg/CU.
// ---------------------------------------------------------------------------
__global__ __launch_bounds__(256, 3) void k_gemm_r(
    const float* __restrict__ x, const bf16s* __restrict__ w1t,
    const float* __restrict__ b1, const float* __restrict__ w2,
    float* __restrict__ partial, bf16s* __restrict__ xb)
{
    __shared__ alignas(16) bf16s As[3][128 * 36];
    __shared__ float gp[2][128];

    const int tid = threadIdx.x;
    const int lane = tid & 63;
    const int wv = tid >> 6;
    const int wr = wv >> 1, wc = wv & 1;
    const int phys = blockIdx.x;
    const int logical = (phys & 7) * 128 + (phys >> 3);   // bijective, XCD-chunked
    const int row0 = (logical >> 2) * 128;
    const int col0 = (logical & 3) * 128;
    const int c0 = lane & 15, khalf = lane >> 4;

    // A staging: thread -> (row ar, 16-col half ah)
    const int ar = tid >> 1, ah = tid & 1;
    const float* xsrc = &x[(size_t)(row0 + ar) * HDIM + ah * 16];
    bf16s* xbdst = &xb[(size_t)(row0 + ar) * HDIM + ah * 16];
    const bool wxb = (col0 == 0);

    // B per-lane fragment base addresses (4 nf), advance by t*32 shorts
    const bf16s* bA[4];
    #pragma unroll
    for (int nf = 0; nf < 4; ++nf)
        bA[nf] = &w1t[(size_t)(col0 + wc * 64 + nf * 16 + c0) * HDIM + khalf * 8];

    f32x4 acc[4][4] = {};
    float4 pa0, pa1, pa2, pa3;

#define LOADPA(T) do { \
        pa0 = *reinterpret_cast<const float4*>(xsrc + (T) * 32);      \
        pa1 = *reinterpret_cast<const float4*>(xsrc + (T) * 32 + 4);  \
        pa2 = *reinterpret_cast<const float4*>(xsrc + (T) * 32 + 8);  \
        pa3 = *reinterpret_cast<const float4*>(xsrc + (T) * 32 + 12); \
    } while (0)

#define STAGE(T, BUF) do { \
        short h[16] = {f2bf(pa0.x), f2bf(pa0.y), f2bf(pa0.z), f2bf(pa0.w),  \
                       f2bf(pa1.x), f2bf(pa1.y), f2bf(pa1.z), f2bf(pa1.w),  \
                       f2bf(pa2.x), f2bf(pa2.y), f2bf(pa2.z), f2bf(pa2.w),  \
                       f2bf(pa3.x), f2bf(pa3.y), f2bf(pa3.z), f2bf(pa3.w)}; \
        *reinterpret_cast<int4*>(&As[BUF][ar * 36 + ah * 16]) =             \
            *reinterpret_cast<const int4*>(&h[0]);                          \
        *reinterpret_cast<int4*>(&As[BUF][ar * 36 + ah * 16 + 8]) =         \
            *reinterpret_cast<const int4*>(&h[8]);                          \
        if (wxb) {                                                          \
            *reinterpret_cast<int4*>(xbdst + (T) * 32) =                    \
                *reinterpret_cast<const int4*>(&h[0]);                      \
            *reinterpret_cast<int4*>(xbdst + (T) * 32 + 8) =                \
                *reinterpret_cast<const int4*>(&h[8]);                      \
        }                                                                   \
    } while (0)

    // prologue: stage tiles 0,1; prefetch pa tile2; B frags tile0 in regs
    LOADPA(0); STAGE(0, 0);
    LOADPA(1); STAGE(1, 1);
    LOADPA(2);
    short8 bv[4], bn[4];
    #pragma unroll
    for (int nf = 0; nf < 4; ++nf)
        bv[nf] = *reinterpret_cast<const short8*>(bA[nf]);
    asm volatile("s_waitcnt lgkmcnt(0)" ::: "memory");
    __builtin_amdgcn_s_barrier();

    for (int t = 0; t < 32; ++t) {
        const int cur = t % 3;
        // issue next-iter B fragment loads (consumed next iter; latency hidden)
        if (t < 31) {
            #pragma unroll
            for (int nf = 0; nf < 4; ++nf)
                bn[nf] = *reinterpret_cast<const short8*>(bA[nf] + (t + 1) * 32);
        }
        // A fragments from LDS (staged two iters ago)
        short8 av[4];
        #pragma unroll
        for (int mf = 0; mf < 4; ++mf) {
            int ra = wr * 64 + mf * 16 + c0;
            av[mf] = *reinterpret_cast<const short8*>(&As[cur][ra * 36 + khalf * 8]);
        }
        __builtin_amdgcn_s_setprio(1);
        #pragma unroll
        for (int nf = 0; nf < 4; ++nf)
            #pragma unroll
            for (int mf = 0; mf < 4; ++mf)
                acc[mf][nf] = __builtin_amdgcn_mfma_f32_16x16x32_bf16(av[mf], bv[nf], acc[mf][nf], 0, 0, 0);
        __builtin_amdgcn_s_setprio(0);

        // stage tile t+2 into buf (t+2)%3 (disjoint from any concurrent reader)
        if (t < 30) STAGE(t + 2, (t + 2) % 3);
        if (t < 29) LOADPA(t + 3);
        #pragma unroll
        for (int nf = 0; nf < 4; ++nf) bv[nf] = bn[nf];

        asm volatile("s_waitcnt lgkmcnt(0)" ::: "memory");
        __builtin_amdgcn_sched_barrier(0);
        __builtin_amdgcn_s_barrier();
    }
#undef LOADPA
#undef STAGE

    // epilogue: per-row partial dot of tanh(h)*W2 over this wave's 64 cols
    float b1v[4], w2v[4];
    #pragma unroll
    for (int nf = 0; nf < 4; ++nf) {
        int gc = col0 + wc * 64 + nf * 16 + c0;
        b1v[nf] = b1[gc];
        w2v[nf] = w2[gc];
    }
    #pragma unroll
    for (int mf = 0; mf < 4; ++mf) {
        #pragma unroll
        for (int reg = 0; reg < 4; ++reg) {
            float s = 0.f;
            #pragma unroll
            for (int nf = 0; nf < 4; ++nf)
                s += fast_tanh(acc[mf][nf][reg] + b1v[nf]) * w2v[nf];
            s += __shfl_xor(s, 1); s += __shfl_xor(s, 2);
            s += __shfl_xor(s, 4); s += __shfl_xor(s, 8);
            if (c0 == 0) gp[wc][wr * 64 + mf * 16 + khalf * 4 + reg] = s;
        }
    }
    __syncthreads();
    if (tid < 128)
        partial[(size_t)(logical & 3) * 32768 + row0 + tid] = gp[0][tid] + gp[1][tid];
}

// ---------------------------------------------------------------------------
// Single-pass per-(b,block): sums the 4 gate partials for member tokens
// (writing gate[] once per valid token), online-softmax stats, ordered lists.
// ---------------------------------------------------------------------------
__global__ void k_blocks(const int* __restrict__ block_ids, const unsigned char* __restrict__ pad,
                         const float* __restrict__ part, const float* __restrict__ b2,
                         float* __restrict__ gate, const int* __restrict__ ct,
                         const float* __restrict__ ct_emb,
                         int* __restrict__ counts, float* __restrict__ mblk,
                         float* __restrict__ wscale, int* __restrict__ lists,
                         float* __restrict__ out_hasb)
{
    const int blk = blockIdx.x;
    const int b = blk >> 7, k = blk & 127;
    const int lane = threadIdx.x;
    const int base = b * NTOK;
    const int lbase = blk * CAP;
    const unsigned long long ltmask = (1ull << lane) - 1ull;
    const float b2v = b2[0];

    float m = -__builtin_inff();
    float s = 0.f;
    int pos = 0;
    for (int t0 = 0; t0 < NTOK; t0 += 64) {
        int t = t0 + lane;
        bool mt = (block_ids[base + t] == k) && (pad[base + t] == 0);
        unsigned long long mask = __ballot(mt);
        if (mt) {
            int r = base + t;
            float g = part[r] + part[32768 + r] + part[65536 + r] + part[98304 + r] + b2v;
            gate[r] = g;   // each valid token belongs to exactly one block
            int my = pos + __popcll(mask & ltmask);
            if (my < CAP) lists[lbase + my] = t;
            float mn = fmaxf(m, g);
            s = s * __expf(m - mn) + __expf(g - mn);
            m = mn;
        }
        pos += __popcll(mask);
    }
    #pragma unroll
    for (int off = 1; off < 64; off <<= 1) {
        float om = __shfl_xor(m, off);
        float os = __shfl_xor(s, off);
        float mn = fmaxf(m, om);
        float sa = (m == -__builtin_inff()) ? 0.f : s * __expf(m - mn);
        float sb = (om == -__builtin_inff()) ? 0.f : os * __expf(om - mn);
        s = sa + sb;
        m = mn;
    }
    if (lane == 0) {
        counts[blk] = pos;
        mblk[blk] = (pos > 0) ? m : 0.f;
        float mod = 1.0f + 0.1f * ct_emb[ct[b] * NBLK + k];
        wscale[blk] = (pos > 0 && s > 0.f) ? (mod / fmaxf(s, 1e-30f)) : 0.f;
        out_hasb[blk] = (pos > 0) ? 1.f : 0.f;
    }
}

// ---------------------------------------------------------------------------
// Pooling from bf16 xb: pooled[b,k,:] = wscale * sum_n exp(gate[n]-m) * xb[b,n,:]
// ---------------------------------------------------------------------------
__global__ void k_pool(const bf16s* __restrict__ xb, const float* __restrict__ gate,
                       const int* __restrict__ lists, const int* __restrict__ counts,
                       const float* __restrict__ mblk, const float* __restrict__ wscale,
                       bf16s* __restrict__ pooled)
{
    const int blk = blockIdx.x;
    const int b = blk >> 7;
    const int tid = threadIdx.x;
    const int base = b * NTOK;
    const int cnt = min(counts[blk], CAP);
    const int lbase = blk * CAP;
    const float m = mblk[blk], ws = wscale[blk];

    float4 acc = {0.f, 0.f, 0.f, 0.f};
    for (int i = 0; i < cnt; ++i) {
        int n = lists[lbase + i];
        float w = __expf(gate[base + n] - m);
        int2 rv = *reinterpret_cast<const int2*>(&xb[(size_t)(base + n) * HDIM + tid * 4]);
        short s4[4];
        *reinterpret_cast<int2*>(s4) = rv;
        unsigned u0 = ((unsigned)(unsigned short)s4[0]) << 16;
        unsigned u1 = ((unsigned)(unsigned short)s4[1]) << 16;
        unsigned u2 = ((unsigned)(unsigned short)s4[2]) << 16;
        unsigned u3 = ((unsigned)(unsigned short)s4[3]) << 16;
        acc.x += w * __builtin_bit_cast(float, u0);
        acc.y += w * __builtin_bit_cast(float, u1);
        acc.z += w * __builtin_bit_cast(float, u2);
        acc.w += w * __builtin_bit_cast(float, u3);
    }
    short o[4] = {f2bf(acc.x * ws), f2bf(acc.y * ws), f2bf(acc.z * ws), f2bf(acc.w * ws)};
    *reinterpret_cast<int2*>(&pooled[(size_t)blk * HDIM + tid * 4]) =
        *reinterpret_cast<const int2*>(o);
}

// ---------------------------------------------------------------------------
// GEMM2: y = pooled @ Wp + bp. 1024^3. 64x64 tiles, 4 waves, dbuf + gll,
// counted-vmcnt schedule (vmcnt(2) in-loop, raw barriers).
// ---------------------------------------------------------------------------
__global__ __launch_bounds__(256) void k_gemm2(
    const bf16s* __restrict__ pooled, const bf16s* __restrict__ wpt,
    const float* __restrict__ bp, float* __restrict__ y)
{
    __shared__ alignas(16) bf16s As[2][64 * 32];
    __shared__ alignas(16) bf16s Bs[2][64 * 32];
    const int tid = threadIdx.x;
    const int lane = tid & 63;
    const int wv = tid >> 6;
    const int wr = wv >> 1, wc = wv & 1;
    const int row0 = (blockIdx.x >> 4) * 64, col0 = (blockIdx.x & 15) * 64;
    const int c0 = lane & 15, khalf = lane >> 4;

    const int sr = wv * 16 + (lane >> 2);
    const int sj = (lane & 3) ^ ((sr >> 1) & 3);
    const int sdst = (wv * 16) * 32 + lane * 8;
    const bf16s* srcA = &pooled[(size_t)(row0 + sr) * 1024 + sj * 8];
    const bf16s* srcB = &wpt[(size_t)(col0 + sr) * 1024 + sj * 8];

    f32x4 acc[2][2] = {};

    gload_lds16(srcA, &As[0][sdst]);
    gload_lds16(srcB, &Bs[0][sdst]);

    for (int t = 0; t < 32; ++t) {
        const int cur = t & 1;
        if (t < 31) {
            gload_lds16(srcA + (t + 1) * 32, &As[cur ^ 1][sdst]);
            gload_lds16(srcB + (t + 1) * 32, &Bs[cur ^ 1][sdst]);
            asm volatile("s_waitcnt vmcnt(2)" ::: "memory");
        } else {
            asm volatile("s_waitcnt vmcnt(0)" ::: "memory");
        }
        __builtin_amdgcn_s_barrier();
        __builtin_amdgcn_sched_barrier(0);
        #pragma unroll
        for (int mf = 0; mf < 2; ++mf) {
            int ra = wr * 32 + mf * 16 + c0;
            short8 av = *reinterpret_cast<const short8*>(
                &As[cur][ra * 32 + ((khalf ^ ((ra >> 1) & 3)) * 8)]);
            #pragma unroll
            for (int nf = 0; nf < 2; ++nf) {
                int rb = wc * 32 + nf * 16 + c0;
                short8 bv = *reinterpret_cast<const short8*>(
                    &Bs[cur][rb * 32 + ((khalf ^ ((rb >> 1) & 3)) * 8)]);
                acc[mf][nf] = __builtin_amdgcn_mfma_f32_16x16x32_bf16(av, bv, acc[mf][nf], 0, 0, 0);
            }
        }
        asm volatile("s_waitcnt lgkmcnt(0)" ::: "memory");
        __builtin_amdgcn_sched_barrier(0);
        __builtin_amdgcn_s_barrier();
    }
    #pragma unroll
    for (int mf = 0; mf < 2; ++mf)
        #pragma unroll
        for (int nf = 0; nf < 2; ++nf)
            #pragma unroll
            for (int reg = 0; reg < 4; ++reg) {
                int grow = row0 + wr * 32 + mf * 16 + khalf * 4 + reg;
                int gcol = col0 + wc * 32 + nf * 16 + c0;
                y[(size_t)grow * 1024 + gcol] = acc[mf][nf][reg] + bp[gcol];
            }
}

// ---------------------------------------------------------------------------
// LayerNorm + ELU + present-mask.
// ---------------------------------------------------------------------------
__global__ void k_lnelu(const float* __restrict__ y, const float* __restrict__ ln_g,
                        const float* __restrict__ ln_b, const int* __restrict__ counts,
                        float* __restrict__ outp)
{
    const int row = blockIdx.x;
    const int k = row & 127;
    const int tid = threadIdx.x;

    float4 v = *reinterpret_cast<const float4*>(&y[(size_t)row * 1024 + tid * 4]);
    float s = v.x + v.y + v.z + v.w;
    float ss = v.x * v.x + v.y * v.y + v.z * v.z + v.w * v.w;
    #pragma unroll
    for (int off = 32; off; off >>= 1) { s += __shfl_xor(s, off); ss += __shfl_xor(ss, off); }

    __shared__ float sbuf[4], ssbuf[4];
    int wv = tid >> 6;
    if ((tid & 63) == 0) { sbuf[wv] = s; ssbuf[wv] = ss; }
    __syncthreads();
    s = sbuf[0] + sbuf[1] + sbuf[2] + sbuf[3];
    ss = ssbuf[0] + ssbuf[1] + ssbuf[2] + ssbuf[3];

    float mu = s * (1.f / 1024.f);
    float var = ss * (1.f / 1024.f) - mu * mu;
    float rstd = rsqrtf(var + 1e-5f);

    bool pres = false;
    #pragma unroll
    for (int bb = 0; bb < 8; ++bb) pres = pres || (counts[bb * NBLK + k] > 0);

    float4 g4 = *reinterpret_cast<const float4*>(&ln_g[tid * 4]);
    float4 b4 = *reinterpret_cast<const float4*>(&ln_b[tid * 4]);
    float vals[4] = {v.x, v.y, v.z, v.w};
    float gs[4] = {g4.x, g4.y, g4.z, g4.w};
    float bs[4] = {b4.x, b4.y, b4.z, b4.w};
    float4 o;
    float* op = &o.x;
    #pragma unroll
    for (int j = 0; j < 4; ++j) {
        float t = (vals[j] - mu) * rstd * gs[j] + bs[j];
        t = (t > 0.f) ? t : expm1f(t);
        op[j] = pres ? t : 0.f;
    }
    *reinterpret_cast<float4*>(&outp[(size_t)row * 1024 + tid * 4]) = o;
}

// ---------------------------------------------------------------------------
extern "C" void kernel_launch(void* const* d_in, const int* in_sizes, int n_in,
                              void* d_out, int out_size, void* d_ws, size_t ws_size,
                              hipStream_t stream)
{
    const float* x      = (const float*)d_in[0];
    const int*   ct     = (const int*)d_in[1];
    const int*   bids   = (const int*)d_in[2];
    const unsigned char* pad = (const unsigned char*)d_in[3];
    const float* W1     = (const float*)d_in[4];
    const float* b1     = (const float*)d_in[5];
    const float* W2     = (const float*)d_in[6];
    const float* b2     = (const float*)d_in[7];
    const float* ct_emb = (const float*)d_in[8];
    const float* Wp     = (const float*)d_in[9];
    const float* bp     = (const float*)d_in[10];
    const float* ln_g   = (const float*)d_in[11];
    const float* ln_b   = (const float*)d_in[12];
    float* outF = (float*)d_out;

    char* ws = (char*)d_ws;
    bf16s* w1t    = (bf16s*)(ws + 0);          //  1,048,576
    bf16s* wpt    = (bf16s*)(ws + 1048576);    //  2,097,152 -> 3,145,728
    float* gate   = (float*)(ws + 3145728);    //    131,072 -> 3,276,800
    float* part   = (float*)(ws + 3276800);    //    524,288 -> 3,801,088
    float* mblk   = (float*)(ws + 3801088);
    float* wscal  = (float*)(ws + 3805184);
    int*   counts = (int*)  (ws + 3809280);
    int*   lists  = (int*)  (ws + 3813376);    //  1,048,576 -> 4,861,952
    bf16s* pooled = (bf16s*)(ws + 4861952);    //  2,097,152 -> 6,959,104
    float* ybuf   = (float*)(ws + 6959104);    //  4,194,304 -> 11,153,408
    bf16s* xb     = (bf16s*)(ws + 11153408);   // 67,108,864 -> 78,262,272

    k_tcvt2<<<dim3(16, 24), 256, 0, stream>>>(W1, Wp, w1t, wpt);
    k_gemm_r<<<1024, 256, 0, stream>>>(x, w1t, b1, W2, part, xb);
    k_blocks<<<1024, 64, 0, stream>>>(bids, pad, part, b2, gate, ct, ct_emb,
                                      counts, mblk, wscal, lists,
                                      outF + (size_t)8 * NBLK * HDIM);
    k_pool<<<1024, 256, 0, stream>>>(xb, gate, lists, counts, mblk, wscal, pooled);
    k_gemm2<<<256, 256, 0, stream>>>(pooled, wpt, bp, ybuf);
    k_lnelu<<<1024, 256, 0, stream>>>(ybuf, ln_g, ln_b, counts, outF);
}

// Round 10
// 148.638 us; speedup vs baseline: 1.3188x; 1.3188x over previous
//
#include <hip/hip_runtime.h>

// (B,N,H,NB,NCT) = (8,4096,1024,128,33), H/2 = 512
#define NTOK 4096
#define HDIM 1024
#define HHALF 512
#define NBLK 128
#define CAP 256
#define XELEMS 33554432ull   // 8*4096*1024

typedef __attribute__((ext_vector_type(8))) short short8;
typedef __attribute__((ext_vector_type(4))) float f32x4;
typedef short bf16s;

__device__ __forceinline__ short f2bf(float f) {
    unsigned u = __builtin_bit_cast(unsigned, f);
    u = (u + 0x7fffu + ((u >> 16) & 1u)) >> 16;   // RNE
    return (short)u;
}
__device__ __forceinline__ void gload_lds16(const void* g, void* l) {
    __builtin_amdgcn_global_load_lds(
        (const __attribute__((address_space(1))) unsigned int*)g,
        (__attribute__((address_space(3))) unsigned int*)l, 16, 0, 0);
}
__device__ __forceinline__ float fast_tanh(float v) {
    float e = __expf(2.0f * v);
    return 1.0f - 2.0f / (e + 1.0f);
}

// ---------------------------------------------------------------------------
// x (f32) -> xb (bf16), grid-stride, vectorized. Memory-bound (roofline ~29us).
// ---------------------------------------------------------------------------
__global__ void k_xcvt(const float* __restrict__ in, bf16s* __restrict__ out) {
    for (size_t i = ((size_t)blockIdx.x * 256 + threadIdx.x) * 8; i < XELEMS;
         i += (size_t)gridDim.x * 256 * 8) {
        float4 a = *reinterpret_cast<const float4*>(&in[i]);
        float4 b = *reinterpret_cast<const float4*>(&in[i + 4]);
        short h[8] = {f2bf(a.x), f2bf(a.y), f2bf(a.z), f2bf(a.w),
                      f2bf(b.x), f2bf(b.y), f2bf(b.z), f2bf(b.w)};
        *reinterpret_cast<int4*>(&out[i]) = *reinterpret_cast<const int4*>(h);
    }
}

// ---------------------------------------------------------------------------
// Tiled transpose+convert for both weights in one launch.
// ---------------------------------------------------------------------------
__global__ void k_tcvt2(const float* __restrict__ W1, const float* __restrict__ Wp,
                        bf16s* __restrict__ w1t, bf16s* __restrict__ wpt) {
    __shared__ float tile[64][65];
    const int by = blockIdx.y;
    const float* in = (by < 8) ? W1 : Wp;
    bf16s* out = (by < 8) ? w1t : wpt;
    const int Nc = (by < 8) ? HHALF : HDIM;
    const int n0 = ((by < 8) ? by : (by - 8)) * 64;
    const int k0 = blockIdx.x * 64;
    const int tx = threadIdx.x & 63, ty = threadIdx.x >> 6;
    #pragma unroll
    for (int i = 0; i < 16; ++i) {
        int r = ty + i * 4;
        tile[r][tx] = in[(size_t)(k0 + r) * Nc + n0 + tx];
    }
    __syncthreads();
    #pragma unroll
    for (int i = 0; i < 16; ++i) {
        int r = ty + i * 4;
        out[(size_t)(n0 + r) * 1024 + k0 + tx] = f2bf(tile[tx][r]);
    }
}

// ---------------------------------------------------------------------------
// Gate GEMM — R6's best-measured schedule, VERBATIM: BK=64, double-buffered
// LDS, counted vmcnt(8) (prefetch stays in flight across barriers), raw
// s_barrier pairs, lgkmcnt(0)+sched_barrier trailing fence (rule 18).
// 128x128 tile, 4 waves (2x2), acc[4][4]. LDS rows 64 shorts; chunk-XOR
// swizzle j^(row&7) both-sides. partial[ct][row] = tanh-dot per col-tile.
// ---------------------------------------------------------------------------
__global__ __launch_bounds__(256, 2) void k_gemm_g(
    const bf16s* __restrict__ xb, const bf16s* __restrict__ w1t,
    const float* __restrict__ b1, const float* __restrict__ w2,
    float* __restrict__ partial)
{
    __shared__ alignas(16) bf16s As[2][128 * 64];
    __shared__ alignas(16) bf16s Bs[2][128 * 64];
    __shared__ float gp[2][128];

    const int tid = threadIdx.x;
    const int lane = tid & 63;
    const int wv = tid >> 6;
    const int wr = wv >> 1, wc = wv & 1;
    const int phys = blockIdx.x;
    const int logical = (phys & 7) * 128 + (phys >> 3);   // 1024 = 8*128 bijective
    const int row0 = (logical >> 2) * 128;
    const int col0 = (logical & 3) * 128;
    const int c0 = lane & 15, khalf = lane >> 4;

    const int srow = wv * 32 + (lane >> 3);
    const int sj   = (lane & 7) ^ (lane >> 3);
    const bf16s* aSrc = &xb [(size_t)(row0 + srow) * HDIM + sj * 8];
    const bf16s* bSrc = &w1t[(size_t)(col0 + srow) * HDIM + sj * 8];
    const int sdst = (wv * 256 + lane) * 8;   // + q*512 shorts

    f32x4 acc[4][4] = {};

    // prologue: issue tile 0 (8 gll in flight)
    #pragma unroll
    for (int q = 0; q < 4; ++q) {
        gload_lds16(aSrc + q * 8 * HDIM, &As[0][sdst + q * 512]);
        gload_lds16(bSrc + q * 8 * HDIM, &Bs[0][sdst + q * 512]);
    }

    for (int t = 0; t < 16; ++t) {
        const int cur = t & 1;
        if (t < 15) {
            const int koff = (t + 1) * 64;
            #pragma unroll
            for (int q = 0; q < 4; ++q) {
                gload_lds16(aSrc + q * 8 * HDIM + koff, &As[cur ^ 1][sdst + q * 512]);
                gload_lds16(bSrc + q * 8 * HDIM + koff, &Bs[cur ^ 1][sdst + q * 512]);
            }
            asm volatile("s_waitcnt vmcnt(8)" ::: "memory");  // tile t done; t+1 in flight
        } else {
            asm volatile("s_waitcnt vmcnt(0)" ::: "memory");
        }
        __builtin_amdgcn_s_barrier();
        __builtin_amdgcn_sched_barrier(0);

        #pragma unroll
        for (int s = 0; s < 2; ++s) {
            short8 av[4], bv[4];
            #pragma unroll
            for (int mf = 0; mf < 4; ++mf) {
                int ra = wr * 64 + mf * 16 + c0;
                int ka = (s * 4 + khalf) ^ (ra & 7);
                av[mf] = *reinterpret_cast<const short8*>(&As[cur][ra * 64 + ka * 8]);
            }
            #pragma unroll
            for (int nf = 0; nf < 4; ++nf) {
                int rb = wc * 64 + nf * 16 + c0;
                int kb = (s * 4 + khalf) ^ (rb & 7);
                bv[nf] = *reinterpret_cast<const short8*>(&Bs[cur][rb * 64 + kb * 8]);
            }
            #pragma unroll
            for (int nf = 0; nf < 4; ++nf)
                #pragma unroll
                for (int mf = 0; mf < 4; ++mf)
                    acc[mf][nf] = __builtin_amdgcn_mfma_f32_16x16x32_bf16(av[mf], bv[nf], acc[mf][nf], 0, 0, 0);
        }

        asm volatile("s_waitcnt lgkmcnt(0)" ::: "memory");
        __builtin_amdgcn_sched_barrier(0);                 // rule 18
        __builtin_amdgcn_s_barrier();                      // buf[cur] free for t+2 gll
    }

    // epilogue: per-row partial dot of tanh(h)*W2 over this wave's 64 cols
    float b1v[4], w2v[4];
    #pragma unroll
    for (int nf = 0; nf < 4; ++nf) {
        int gc = col0 + wc * 64 + nf * 16 + c0;
        b1v[nf] = b1[gc];
        w2v[nf] = w2[gc];
    }
    #pragma unroll
    for (int mf = 0; mf < 4; ++mf) {
        #pragma unroll
        for (int reg = 0; reg < 4; ++reg) {
            float s = 0.f;
            #pragma unroll
            for (int nf = 0; nf < 4; ++nf)
                s += fast_tanh(acc[mf][nf][reg] + b1v[nf]) * w2v[nf];
            s += __shfl_xor(s, 1); s += __shfl_xor(s, 2);
            s += __shfl_xor(s, 4); s += __shfl_xor(s, 8);
            if (c0 == 0) gp[wc][wr * 64 + mf * 16 + khalf * 4 + reg] = s;
        }
    }
    __syncthreads();
    if (tid < 128)
        partial[(size_t)(logical & 3) * 32768 + row0 + tid] = gp[0][tid] + gp[1][tid];
}

// ---------------------------------------------------------------------------
// Single-pass per-(b,block): sums the 4 gate partials for member tokens
// (writing gate[] once per valid token), online-softmax stats, ordered lists.
// ---------------------------------------------------------------------------
__global__ void k_blocks(const int* __restrict__ block_ids, const unsigned char* __restrict__ pad,
                         const float* __restrict__ part, const float* __restrict__ b2,
                         float* __restrict__ gate, const int* __restrict__ ct,
                         const float* __restrict__ ct_emb,
                         int* __restrict__ counts, float* __restrict__ mblk,
                         float* __restrict__ wscale, int* __restrict__ lists,
                         float* __restrict__ out_hasb)
{
    const int blk = blockIdx.x;
    const int b = blk >> 7, k = blk & 127;
    const int lane = threadIdx.x;
    const int base = b * NTOK;
    const int lbase = blk * CAP;
    const unsigned long long ltmask = (1ull << lane) - 1ull;
    const float b2v = b2[0];

    float m = -__builtin_inff();
    float s = 0.f;
    int pos = 0;
    for (int t0 = 0; t0 < NTOK; t0 += 64) {
        int t = t0 + lane;
        bool mt = (block_ids[base + t] == k) && (pad[base + t] == 0);
        unsigned long long mask = __ballot(mt);
        if (mt) {
            int r = base + t;
            float g = part[r] + part[32768 + r] + part[65536 + r] + part[98304 + r] + b2v;
            gate[r] = g;   // each valid token belongs to exactly one block
            int my = pos + __popcll(mask & ltmask);
            if (my < CAP) lists[lbase + my] = t;
            float mn = fmaxf(m, g);
            s = s * __expf(m - mn) + __expf(g - mn);
            m = mn;
        }
        pos += __popcll(mask);
    }
    #pragma unroll
    for (int off = 1; off < 64; off <<= 1) {
        float om = __shfl_xor(m, off);
        float os = __shfl_xor(s, off);
        float mn = fmaxf(m, om);
        float sa = (m == -__builtin_inff()) ? 0.f : s * __expf(m - mn);
        float sb = (om == -__builtin_inff()) ? 0.f : os * __expf(om - mn);
        s = sa + sb;
        m = mn;
    }
    if (lane == 0) {
        counts[blk] = pos;
        mblk[blk] = (pos > 0) ? m : 0.f;
        float mod = 1.0f + 0.1f * ct_emb[ct[b] * NBLK + k];
        wscale[blk] = (pos > 0 && s > 0.f) ? (mod / fmaxf(s, 1e-30f)) : 0.f;
        out_hasb[blk] = (pos > 0) ? 1.f : 0.f;
    }
}

// ---------------------------------------------------------------------------
// Pooling from bf16 xb: pooled[b,k,:] = wscale * sum_n exp(gate[n]-m) * xb[b,n,:]
// ---------------------------------------------------------------------------
__global__ void k_pool(const bf16s* __restrict__ xb, const float* __restrict__ gate,
                       const int* __restrict__ lists, const int* __restrict__ counts,
                       const float* __restrict__ mblk, const float* __restrict__ wscale,
                       bf16s* __restrict__ pooled)
{
    const int blk = blockIdx.x;
    const int b = blk >> 7;
    const int tid = threadIdx.x;
    const int base = b * NTOK;
    const int cnt = min(counts[blk], CAP);
    const int lbase = blk * CAP;
    const float m = mblk[blk], ws = wscale[blk];

    float4 acc = {0.f, 0.f, 0.f, 0.f};
    for (int i = 0; i < cnt; ++i) {
        int n = lists[lbase + i];
        float w = __expf(gate[base + n] - m);
        int2 rv = *reinterpret_cast<const int2*>(&xb[(size_t)(base + n) * HDIM + tid * 4]);
        short s4[4];
        *reinterpret_cast<int2*>(s4) = rv;
        unsigned u0 = ((unsigned)(unsigned short)s4[0]) << 16;
        unsigned u1 = ((unsigned)(unsigned short)s4[1]) << 16;
        unsigned u2 = ((unsigned)(unsigned short)s4[2]) << 16;
        unsigned u3 = ((unsigned)(unsigned short)s4[3]) << 16;
        acc.x += w * __builtin_bit_cast(float, u0);
        acc.y += w * __builtin_bit_cast(float, u1);
        acc.z += w * __builtin_bit_cast(float, u2);
        acc.w += w * __builtin_bit_cast(float, u3);
    }
    short o[4] = {f2bf(acc.x * ws), f2bf(acc.y * ws), f2bf(acc.z * ws), f2bf(acc.w * ws)};
    *reinterpret_cast<int2*>(&pooled[(size_t)blk * HDIM + tid * 4]) =
        *reinterpret_cast<const int2*>(o);
}

// ---------------------------------------------------------------------------
// GEMM2: y = pooled @ Wp + bp. 1024^3. 64x64 tiles, 4 waves, dbuf + gll,
// counted-vmcnt schedule (vmcnt(2) in-loop, raw barriers).
// ---------------------------------------------------------------------------
__global__ __launch_bounds__(256) void k_gemm2(
    const bf16s* __restrict__ pooled, const bf16s* __restrict__ wpt,
    const float* __restrict__ bp, float* __restrict__ y)
{
    __shared__ alignas(16) bf16s As[2][64 * 32];
    __shared__ alignas(16) bf16s Bs[2][64 * 32];
    const int tid = threadIdx.x;
    const int lane = tid & 63;
    const int wv = tid >> 6;
    const int wr = wv >> 1, wc = wv & 1;
    const int row0 = (blockIdx.x >> 4) * 64, col0 = (blockIdx.x & 15) * 64;
    const int c0 = lane & 15, khalf = lane >> 4;

    const int sr = wv * 16 + (lane >> 2);
    const int sj = (lane & 3) ^ ((sr >> 1) & 3);
    const int sdst = (wv * 16) * 32 + lane * 8;
    const bf16s* srcA = &pooled[(size_t)(row0 + sr) * 1024 + sj * 8];
    const bf16s* srcB = &wpt[(size_t)(col0 + sr) * 1024 + sj * 8];

    f32x4 acc[2][2] = {};

    gload_lds16(srcA, &As[0][sdst]);
    gload_lds16(srcB, &Bs[0][sdst]);

    for (int t = 0; t < 32; ++t) {
        const int cur = t & 1;
        if (t < 31) {
            gload_lds16(srcA + (t + 1) * 32, &As[cur ^ 1][sdst]);
            gload_lds16(srcB + (t + 1) * 32, &Bs[cur ^ 1][sdst]);
            asm volatile("s_waitcnt vmcnt(2)" ::: "memory");
        } else {
            asm volatile("s_waitcnt vmcnt(0)" ::: "memory");
        }
        __builtin_amdgcn_s_barrier();
        __builtin_amdgcn_sched_barrier(0);
        #pragma unroll
        for (int mf = 0; mf < 2; ++mf) {
            int ra = wr * 32 + mf * 16 + c0;
            short8 av = *reinterpret_cast<const short8*>(
                &As[cur][ra * 32 + ((khalf ^ ((ra >> 1) & 3)) * 8)]);
            #pragma unroll
            for (int nf = 0; nf < 2; ++nf) {
                int rb = wc * 32 + nf * 16 + c0;
                short8 bv = *reinterpret_cast<const short8*>(
                    &Bs[cur][rb * 32 + ((khalf ^ ((rb >> 1) & 3)) * 8)]);
                acc[mf][nf] = __builtin_amdgcn_mfma_f32_16x16x32_bf16(av, bv, acc[mf][nf], 0, 0, 0);
            }
        }
        asm volatile("s_waitcnt lgkmcnt(0)" ::: "memory");
        __builtin_amdgcn_sched_barrier(0);
        __builtin_amdgcn_s_barrier();
    }
    #pragma unroll
    for (int mf = 0; mf < 2; ++mf)
        #pragma unroll
        for (int nf = 0; nf < 2; ++nf)
            #pragma unroll
            for (int reg = 0; reg < 4; ++reg) {
                int grow = row0 + wr * 32 + mf * 16 + khalf * 4 + reg;
                int gcol = col0 + wc * 32 + nf * 16 + c0;
                y[(size_t)grow * 1024 + gcol] = acc[mf][nf][reg] + bp[gcol];
            }
}

// ---------------------------------------------------------------------------
// LayerNorm + ELU + present-mask.
// ---------------------------------------------------------------------------
__global__ void k_lnelu(const float* __restrict__ y, const float* __restrict__ ln_g,
                        const float* __restrict__ ln_b, const int* __restrict__ counts,
                        float* __restrict__ outp)
{
    const int row = blockIdx.x;
    const int k = row & 127;
    const int tid = threadIdx.x;

    float4 v = *reinterpret_cast<const float4*>(&y[(size_t)row * 1024 + tid * 4]);
    float s = v.x + v.y + v.z + v.w;
    float ss = v.x * v.x + v.y * v.y + v.z * v.z + v.w * v.w;
    #pragma unroll
    for (int off = 32; off; off >>= 1) { s += __shfl_xor(s, off); ss += __shfl_xor(ss, off); }

    __shared__ float sbuf[4], ssbuf[4];
    int wv = tid >> 6;
    if ((tid & 63) == 0) { sbuf[wv] = s; ssbuf[wv] = ss; }
    __syncthreads();
    s = sbuf[0] + sbuf[1] + sbuf[2] + sbuf[3];
    ss = ssbuf[0] + ssbuf[1] + ssbuf[2] + ssbuf[3];

    float mu = s * (1.f / 1024.f);
    float var = ss * (1.f / 1024.f) - mu * mu;
    float rstd = rsqrtf(var + 1e-5f);

    bool pres = false;
    #pragma unroll
    for (int bb = 0; bb < 8; ++bb) pres = pres || (counts[bb * NBLK + k] > 0);

    float4 g4 = *reinterpret_cast<const float4*>(&ln_g[tid * 4]);
    float4 b4 = *reinterpret_cast<const float4*>(&ln_b[tid * 4]);
    float vals[4] = {v.x, v.y, v.z, v.w};
    float gs[4] = {g4.x, g4.y, g4.z, g4.w};
    float bs[4] = {b4.x, b4.y, b4.z, b4.w};
    float4 o;
    float* op = &o.x;
    #pragma unroll
    for (int j = 0; j < 4; ++j) {
        float t = (vals[j] - mu) * rstd * gs[j] + bs[j];
        t = (t > 0.f) ? t : expm1f(t);
        op[j] = pres ? t : 0.f;
    }
    *reinterpret_cast<float4*>(&outp[(size_t)row * 1024 + tid * 4]) = o;
}

// ---------------------------------------------------------------------------
extern "C" void kernel_launch(void* const* d_in, const int* in_sizes, int n_in,
                              void* d_out, int out_size, void* d_ws, size_t ws_size,
                              hipStream_t stream)
{
    const float* x      = (const float*)d_in[0];
    const int*   ct     = (const int*)d_in[1];
    const int*   bids   = (const int*)d_in[2];
    const unsigned char* pad = (const unsigned char*)d_in[3];
    const float* W1     = (const float*)d_in[4];
    const float* b1     = (const float*)d_in[5];
    const float* W2     = (const float*)d_in[6];
    const float* b2     = (const float*)d_in[7];
    const float* ct_emb = (const float*)d_in[8];
    const float* Wp     = (const float*)d_in[9];
    const float* bp     = (const float*)d_in[10];
    const float* ln_g   = (const float*)d_in[11];
    const float* ln_b   = (const float*)d_in[12];
    float* outF = (float*)d_out;

    char* ws = (char*)d_ws;
    bf16s* w1t    = (bf16s*)(ws + 0);          //  1,048,576
    bf16s* wpt    = (bf16s*)(ws + 1048576);    //  2,097,152 -> 3,145,728
    float* gate   = (float*)(ws + 3145728);    //    131,072 -> 3,276,800
    float* part   = (float*)(ws + 3276800);    //    524,288 -> 3,801,088
    float* mblk   = (float*)(ws + 3801088);
    float* wscal  = (float*)(ws + 3805184);
    int*   counts = (int*)  (ws + 3809280);
    int*   lists  = (int*)  (ws + 3813376);    //  1,048,576 -> 4,861,952
    bf16s* pooled = (bf16s*)(ws + 4861952);    //  2,097,152 -> 6,959,104
    float* ybuf   = (float*)(ws + 6959104);    //  4,194,304 -> 11,153,408
    bf16s* xb     = (bf16s*)(ws + 11153408);   // 67,108,864 -> 78,262,272

    k_tcvt2<<<dim3(16, 24), 256, 0, stream>>>(W1, Wp, w1t, wpt);
    k_xcvt<<<2048, 256, 0, stream>>>(x, xb);
    k_gemm_g<<<1024, 256, 0, stream>>>(xb, w1t, b1, W2, part);
    k_blocks<<<1024, 64, 0, stream>>>(bids, pad, part, b2, gate, ct, ct_emb,
                                      counts, mblk, wscal, lists,
                                      outF + (size_t)8 * NBLK * HDIM);
    k_pool<<<1024, 256, 0, stream>>>(xb, gate, lists, counts, mblk, wscal, pooled);
    k_gemm2<<<256, 256, 0, stream>>>(pooled, wpt, bp, ybuf);
    k_lnelu<<<1024, 256, 0, stream>>>(ybuf, ln_g, ln_b, counts, outF);
}

// Round 11
// 144.270 us; speedup vs baseline: 1.3587x; 1.0303x over previous
//
#include <hip/hip_runtime.h>

// (B,N,H,NB,NCT) = (8,4096,1024,128,33), H/2 = 512
#define NTOK 4096
#define HDIM 1024
#define HHALF 512
#define NBLK 128
#define CAP 256
#define XELEMS 33554432ull   // 8*4096*1024

typedef __attribute__((ext_vector_type(8))) short short8;
typedef __attribute__((ext_vector_type(4))) float f32x4;
typedef short bf16s;

__device__ __forceinline__ short f2bf(float f) {
    unsigned u = __builtin_bit_cast(unsigned, f);
    u = (u + 0x7fffu + ((u >> 16) & 1u)) >> 16;   // RNE
    return (short)u;
}
__device__ __forceinline__ void gload_lds16(const void* g, void* l) {
    __builtin_amdgcn_global_load_lds(
        (const __attribute__((address_space(1))) unsigned int*)g,
        (__attribute__((address_space(3))) unsigned int*)l, 16, 0, 0);
}
__device__ __forceinline__ float fast_tanh(float v) {
    float e = __expf(2.0f * v);
    return 1.0f - 2.0f / (e + 1.0f);
}

// ---------------------------------------------------------------------------
// x (f32) -> xb (bf16). Memory-bound (roofline ~29us).
// ---------------------------------------------------------------------------
__global__ void k_xcvt(const float* __restrict__ in, bf16s* __restrict__ out) {
    for (size_t i = ((size_t)blockIdx.x * 256 + threadIdx.x) * 8; i < XELEMS;
         i += (size_t)gridDim.x * 256 * 8) {
        float4 a = *reinterpret_cast<const float4*>(&in[i]);
        float4 b = *reinterpret_cast<const float4*>(&in[i + 4]);
        short h[8] = {f2bf(a.x), f2bf(a.y), f2bf(a.z), f2bf(a.w),
                      f2bf(b.x), f2bf(b.y), f2bf(b.z), f2bf(b.w)};
        *reinterpret_cast<int4*>(&out[i]) = *reinterpret_cast<const int4*>(h);
    }
}

// ---------------------------------------------------------------------------
// Tiled transpose+convert for both weights.
// ---------------------------------------------------------------------------
__global__ void k_tcvt2(const float* __restrict__ W1, const float* __restrict__ Wp,
                        bf16s* __restrict__ w1t, bf16s* __restrict__ wpt) {
    __shared__ float tile[64][65];
    const int by = blockIdx.y;
    const float* in = (by < 8) ? W1 : Wp;
    bf16s* out = (by < 8) ? w1t : wpt;
    const int Nc = (by < 8) ? HHALF : HDIM;
    const int n0 = ((by < 8) ? by : (by - 8)) * 64;
    const int k0 = blockIdx.x * 64;
    const int tx = threadIdx.x & 63, ty = threadIdx.x >> 6;
    #pragma unroll
    for (int i = 0; i < 16; ++i) {
        int r = ty + i * 4;
        tile[r][tx] = in[(size_t)(k0 + r) * Nc + n0 + tx];
    }
    __syncthreads();
    #pragma unroll
    for (int i = 0; i < 16; ++i) {
        int r = ty + i * 4;
        out[(size_t)(n0 + r) * 1024 + k0 + tx] = f2bf(tile[tx][r]);
    }
}

// ---------------------------------------------------------------------------
// Gate GEMM — 8-phase-style 256x256 tile (m201-template port).
// BK=32, 32 K-tiles, 2 phases/tile (m-half). 512 thr = 8 waves (2m x 4n),
// per-wave output 128x64, acc[8][4]. Per phase: {2 gll stage | ds_reads |
// barrier | lgkmcnt(0) | 16 MFMA | barrier}; vmcnt(4) ONLY at tile-start
// (counted — loads stay in flight across barriers; drain only at the end).
// B read once per tile into regs (reused by both phases).
// Staging targets only regions certified dead by a prior barrier:
//   A m-strip q of buf dies after phase q; B of buf dies after phase 0.
// Stage schedule (2 gll each): P0: A-s1,B-s1 of tile kb -> buf1;
//   P1: A-s0,B-s0(ka+2)->buf0; P2: A-s1,B-s1(ka+2)->buf0;
//   P3: A-s0,B-s0(kb+2)->buf1.  vmcnt(4) at P0/P2 waits 4+-phase-old loads.
// LDS 64 KB. Swizzle key (row>>1)&3 -> 2-way conflicts (free, m136).
// ---------------------------------------------------------------------------
__global__ __launch_bounds__(512, 1) void k_gemm8(
    const bf16s* __restrict__ xb, const bf16s* __restrict__ w1t,
    const float* __restrict__ b1, const float* __restrict__ w2,
    float* __restrict__ partial)
{
    __shared__ alignas(16) bf16s As[2][256 * 32];
    __shared__ alignas(16) bf16s Bs[2][256 * 32];

    const int tid = threadIdx.x;
    const int lane = tid & 63;
    const int wv = tid >> 6;           // 0..7
    const int wm = wv >> 2;            // 0..1
    const int wn = wv & 3;             // 0..3
    const int phys = blockIdx.x;
    const int logical = (phys & 7) * 32 + (phys >> 3);  // 256 = 8*32 bijective
    const int row0 = (logical >> 1) * 256;
    const int ct   = logical & 1;
    const int col0 = ct * 256;
    const int c0 = lane & 15, khalf = lane >> 4;

    // staging: per gll slot a wave covers 16 consecutive rows (64 lanes*16B=1KB)
    // source chunk pre-swizzled: sj = (lane&3) ^ ((row>>1)&3), row = 16k+(lane>>2)
    const int sj = (lane & 3) ^ ((lane >> 3) & 3);
    const int rA0 = ((wv & 4) ? 128 : 0) + (wv & 3) * 16 + (lane >> 2);  // strip0 row
    const int rB0 = wv * 16 + (lane >> 2);                               // B-half0 row
    const bf16s* aS0 = &xb [(size_t)(row0 + rA0) * HDIM + sj * 8];
    const bf16s* aS1 = aS0 + (size_t)64 * HDIM;    // strip1 = +64 rows
    const bf16s* bS0 = &w1t[(size_t)(col0 + rB0) * HDIM + sj * 8];
    const bf16s* bS1 = bS0 + (size_t)128 * HDIM;   // B-half1 = +128 rows
    const int adst0 = (((wv & 4) ? 128 : 0) + (wv & 3) * 16) * 32 + lane * 8;
    const int adst1 = adst0 + 64 * 32;
    const int bdst0 = (wv * 16) * 32 + lane * 8;
    const int bdst1 = bdst0 + 128 * 32;

    // fragment reads: chunk = khalf ^ ((row>>1)&3); row = .. + c0 -> key (c0>>1)&3
    const int ch8 = (khalf ^ ((c0 >> 1) & 3)) * 8;
    const int arA = (wm * 128 + c0) * 32 + ch8;   // + mf*512
    const int brB = (wn * 64 + c0) * 32 + ch8;    // + nf*512

    f32x4 acc[8][4] = {};
    short8 bvv[4];
    short8 av[4];

#define MFMA16(MB)                                                            \
    __builtin_amdgcn_s_setprio(1);                                           \
    _Pragma("unroll")                                                         \
    for (int n = 0; n < 4; ++n)                                               \
        _Pragma("unroll")                                                     \
        for (int m = 0; m < 4; ++m)                                           \
            acc[(MB) + m][n] =                                                \
                __builtin_amdgcn_mfma_f32_16x16x32_bf16(av[m], bvv[n],        \
                                                        acc[(MB) + m][n], 0, 0, 0); \
    __builtin_amdgcn_s_setprio(0);

    // prologue: tile0 full (buf0), tile1 A-s0+B-s0 (buf1)  [6 gll in flight]
    gload_lds16(aS0, &As[0][adst0]);
    gload_lds16(aS1, &As[0][adst1]);
    gload_lds16(bS0, &Bs[0][bdst0]);
    gload_lds16(bS1, &Bs[0][bdst1]);
    gload_lds16(aS0 + 32, &As[1][adst0]);
    gload_lds16(bS0 + 32, &Bs[1][bdst0]);

    for (int it = 0; it < 16; ++it) {
        const int ka = 2 * it, kb = 2 * it + 1;
        const bool nl = (it < 15);

        // ===== P0: tile ka, buf0, m-half 0 =====
        gload_lds16(aS1 + kb * 32, &As[1][adst1]);   // finish tile kb staging
        gload_lds16(bS1 + kb * 32, &Bs[1][bdst1]);
        asm volatile("s_waitcnt vmcnt(4)" ::: "memory");   // tile ka resident
        __builtin_amdgcn_s_barrier();                      // cross-wave certify
        #pragma unroll
        for (int m = 0; m < 4; ++m)
            av[m] = *reinterpret_cast<const short8*>(&As[0][arA + m * 512]);
        #pragma unroll
        for (int n = 0; n < 4; ++n)
            bvv[n] = *reinterpret_cast<const short8*>(&Bs[0][brB + n * 512]);
        asm volatile("s_waitcnt lgkmcnt(0)" ::: "memory");
        __builtin_amdgcn_sched_barrier(0);
        MFMA16(0)
        __builtin_amdgcn_s_barrier();

        // ===== P1: tile ka, buf0, m-half 1 =====
        #pragma unroll
        for (int m = 0; m < 4; ++m)
            av[m] = *reinterpret_cast<const short8*>(&As[0][arA + (4 + m) * 512]);
        if (nl) {
            gload_lds16(aS0 + (ka + 2) * 32, &As[0][adst0]);  // strip0 dead @P0
            gload_lds16(bS0 + (ka + 2) * 32, &Bs[0][bdst0]);  // B buf0 dead @P0
        }
        __builtin_amdgcn_s_barrier();
        asm volatile("s_waitcnt lgkmcnt(0)" ::: "memory");
        __builtin_amdgcn_sched_barrier(0);
        MFMA16(4)
        __builtin_amdgcn_s_barrier();

        // ===== P2: tile kb, buf1, m-half 0 =====
        if (nl) {
            gload_lds16(aS1 + (ka + 2) * 32, &As[0][adst1]);  // strip1 dead @P1
            gload_lds16(bS1 + (ka + 2) * 32, &Bs[0][bdst1]);
            asm volatile("s_waitcnt vmcnt(4)" ::: "memory");  // tile kb resident
        } else {
            asm volatile("s_waitcnt vmcnt(0)" ::: "memory");
        }
        __builtin_amdgcn_s_barrier();
        #pragma unroll
        for (int m = 0; m < 4; ++m)
            av[m] = *reinterpret_cast<const short8*>(&As[1][arA + m * 512]);
        #pragma unroll
        for (int n = 0; n < 4; ++n)
            bvv[n] = *reinterpret_cast<const short8*>(&Bs[1][brB + n * 512]);
        asm volatile("s_waitcnt lgkmcnt(0)" ::: "memory");
        __builtin_amdgcn_sched_barrier(0);
        MFMA16(0)
        __builtin_amdgcn_s_barrier();

        // ===== P3: tile kb, buf1, m-half 1 =====
        #pragma unroll
        for (int m = 0; m < 4; ++m)
            av[m] = *reinterpret_cast<const short8*>(&As[1][arA + (4 + m) * 512]);
        if (nl) {
            gload_lds16(aS0 + (kb + 2) * 32, &As[1][adst0]);  // buf1 s0 dead @P2
            gload_lds16(bS0 + (kb + 2) * 32, &Bs[1][bdst0]);  // buf1 B dead @P2
        }
        __builtin_amdgcn_s_barrier();
        asm volatile("s_waitcnt lgkmcnt(0)" ::: "memory");
        __builtin_amdgcn_sched_barrier(0);
        MFMA16(4)
        __builtin_amdgcn_s_barrier();
    }
#undef MFMA16

    // epilogue: per-row dot of tanh(h)*W2 over this wave's 64 cols;
    // gp[4][256] aliased into As (all LDS reads drained).
    float* gp = reinterpret_cast<float*>(&As[0][0]);
    float b1v[4], w2v[4];
    #pragma unroll
    for (int nf = 0; nf < 4; ++nf) {
        int gc = col0 + wn * 64 + nf * 16 + c0;
        b1v[nf] = b1[gc];
        w2v[nf] = w2[gc];
    }
    #pragma unroll
    for (int mf = 0; mf < 8; ++mf) {
        #pragma unroll
        for (int reg = 0; reg < 4; ++reg) {
            float s = 0.f;
            #pragma unroll
            for (int nf = 0; nf < 4; ++nf)
                s += fast_tanh(acc[mf][nf][reg] + b1v[nf]) * w2v[nf];
            s += __shfl_xor(s, 1); s += __shfl_xor(s, 2);
            s += __shfl_xor(s, 4); s += __shfl_xor(s, 8);
            if (c0 == 0)
                gp[wn * 256 + wm * 128 + mf * 16 + khalf * 4 + reg] = s;
        }
    }
    __syncthreads();
    if (tid < 256)
        partial[(size_t)ct * 32768 + row0 + tid] =
            gp[tid] + gp[256 + tid] + gp[512 + tid] + gp[768 + tid];
}

// ---------------------------------------------------------------------------
// Single-pass per-(b,block): sums the 2 gate partials for member tokens,
// online-softmax stats, ordered lists.
// ---------------------------------------------------------------------------
__global__ void k_blocks(const int* __restrict__ block_ids, const unsigned char* __restrict__ pad,
                         const float* __restrict__ part, const float* __restrict__ b2,
                         float* __restrict__ gate, const int* __restrict__ ct,
                         const float* __restrict__ ct_emb,
                         int* __restrict__ counts, float* __restrict__ mblk,
                         float* __restrict__ wscale, int* __restrict__ lists,
                         float* __restrict__ out_hasb)
{
    const int blk = blockIdx.x;
    const int b = blk >> 7, k = blk & 127;
    const int lane = threadIdx.x;
    const int base = b * NTOK;
    const int lbase = blk * CAP;
    const unsigned long long ltmask = (1ull << lane) - 1ull;
    const float b2v = b2[0];

    float m = -__builtin_inff();
    float s = 0.f;
    int pos = 0;
    for (int t0 = 0; t0 < NTOK; t0 += 64) {
        int t = t0 + lane;
        bool mt = (block_ids[base + t] == k) && (pad[base + t] == 0);
        unsigned long long mask = __ballot(mt);
        if (mt) {
            int r = base + t;
            float g = part[r] + part[32768 + r] + b2v;
            gate[r] = g;   // each valid token belongs to exactly one block
            int my = pos + __popcll(mask & ltmask);
            if (my < CAP) lists[lbase + my] = t;
            float mn = fmaxf(m, g);
            s = s * __expf(m - mn) + __expf(g - mn);
            m = mn;
        }
        pos += __popcll(mask);
    }
    #pragma unroll
    for (int off = 1; off < 64; off <<= 1) {
        float om = __shfl_xor(m, off);
        float os = __shfl_xor(s, off);
        float mn = fmaxf(m, om);
        float sa = (m == -__builtin_inff()) ? 0.f : s * __expf(m - mn);
        float sb = (om == -__builtin_inff()) ? 0.f : os * __expf(om - mn);
        s = sa + sb;
        m = mn;
    }
    if (lane == 0) {
        counts[blk] = pos;
        mblk[blk] = (pos > 0) ? m : 0.f;
        float mod = 1.0f + 0.1f * ct_emb[ct[b] * NBLK + k];
        wscale[blk] = (pos > 0 && s > 0.f) ? (mod / fmaxf(s, 1e-30f)) : 0.f;
        out_hasb[blk] = (pos > 0) ? 1.f : 0.f;
    }
}

// ---------------------------------------------------------------------------
// Pooling from bf16 xb.
// ---------------------------------------------------------------------------
__global__ void k_pool(const bf16s* __restrict__ xb, const float* __restrict__ gate,
                       const int* __restrict__ lists, const int* __restrict__ counts,
                       const float* __restrict__ mblk, const float* __restrict__ wscale,
                       bf16s* __restrict__ pooled)
{
    const int blk = blockIdx.x;
    const int b = blk >> 7;
    const int tid = threadIdx.x;
    const int base = b * NTOK;
    const int cnt = min(counts[blk], CAP);
    const int lbase = blk * CAP;
    const float m = mblk[blk], ws = wscale[blk];

    float4 acc = {0.f, 0.f, 0.f, 0.f};
    for (int i = 0; i < cnt; ++i) {
        int n = lists[lbase + i];
        float w = __expf(gate[base + n] - m);
        int2 rv = *reinterpret_cast<const int2*>(&xb[(size_t)(base + n) * HDIM + tid * 4]);
        short s4[4];
        *reinterpret_cast<int2*>(s4) = rv;
        unsigned u0 = ((unsigned)(unsigned short)s4[0]) << 16;
        unsigned u1 = ((unsigned)(unsigned short)s4[1]) << 16;
        unsigned u2 = ((unsigned)(unsigned short)s4[2]) << 16;
        unsigned u3 = ((unsigned)(unsigned short)s4[3]) << 16;
        acc.x += w * __builtin_bit_cast(float, u0);
        acc.y += w * __builtin_bit_cast(float, u1);
        acc.z += w * __builtin_bit_cast(float, u2);
        acc.w += w * __builtin_bit_cast(float, u3);
    }
    short o[4] = {f2bf(acc.x * ws), f2bf(acc.y * ws), f2bf(acc.z * ws), f2bf(acc.w * ws)};
    *reinterpret_cast<int2*>(&pooled[(size_t)blk * HDIM + tid * 4]) =
        *reinterpret_cast<const int2*>(o);
}

// ---------------------------------------------------------------------------
// GEMM2: y = pooled @ Wp + bp. 1024^3. 64x64 tiles, 4 waves, dbuf + gll,
// counted-vmcnt schedule.
// ---------------------------------------------------------------------------
__global__ __launch_bounds__(256) void k_gemm2(
    const bf16s* __restrict__ pooled, const bf16s* __restrict__ wpt,
    const float* __restrict__ bp, float* __restrict__ y)
{
    __shared__ alignas(16) bf16s As[2][64 * 32];
    __shared__ alignas(16) bf16s Bs[2][64 * 32];
    const int tid = threadIdx.x;
    const int lane = tid & 63;
    const int wv = tid >> 6;
    const int wr = wv >> 1, wc = wv & 1;
    const int row0 = (blockIdx.x >> 4) * 64, col0 = (blockIdx.x & 15) * 64;
    const int c0 = lane & 15, khalf = lane >> 4;

    const int sr = wv * 16 + (lane >> 2);
    const int sj = (lane & 3) ^ ((sr >> 1) & 3);
    const int sdst = (wv * 16) * 32 + lane * 8;
    const bf16s* srcA = &pooled[(size_t)(row0 + sr) * 1024 + sj * 8];
    const bf16s* srcB = &wpt[(size_t)(col0 + sr) * 1024 + sj * 8];

    f32x4 acc[2][2] = {};

    gload_lds16(srcA, &As[0][sdst]);
    gload_lds16(srcB, &Bs[0][sdst]);

    for (int t = 0; t < 32; ++t) {
        const int cur = t & 1;
        if (t < 31) {
            gload_lds16(srcA + (t + 1) * 32, &As[cur ^ 1][sdst]);
            gload_lds16(srcB + (t + 1) * 32, &Bs[cur ^ 1][sdst]);
            asm volatile("s_waitcnt vmcnt(2)" ::: "memory");
        } else {
            asm volatile("s_waitcnt vmcnt(0)" ::: "memory");
        }
        __builtin_amdgcn_s_barrier();
        __builtin_amdgcn_sched_barrier(0);
        #pragma unroll
        for (int mf = 0; mf < 2; ++mf) {
            int ra = wr * 32 + mf * 16 + c0;
            short8 av = *reinterpret_cast<const short8*>(
                &As[cur][ra * 32 + ((khalf ^ ((ra >> 1) & 3)) * 8)]);
            #pragma unroll
            for (int nf = 0; nf < 2; ++nf) {
                int rb = wc * 32 + nf * 16 + c0;
                short8 bv = *reinterpret_cast<const short8*>(
                    &Bs[cur][rb * 32 + ((khalf ^ ((rb >> 1) & 3)) * 8)]);
                acc[mf][nf] = __builtin_amdgcn_mfma_f32_16x16x32_bf16(av, bv, acc[mf][nf], 0, 0, 0);
            }
        }
        asm volatile("s_waitcnt lgkmcnt(0)" ::: "memory");
        __builtin_amdgcn_sched_barrier(0);
        __builtin_amdgcn_s_barrier();
    }
    #pragma unroll
    for (int mf = 0; mf < 2; ++mf)
        #pragma unroll
        for (int nf = 0; nf < 2; ++nf)
            #pragma unroll
            for (int reg = 0; reg < 4; ++reg) {
                int grow = row0 + wr * 32 + mf * 16 + khalf * 4 + reg;
                int gcol = col0 + wc * 32 + nf * 16 + c0;
                y[(size_t)grow * 1024 + gcol] = acc[mf][nf][reg] + bp[gcol];
            }
}

// ---------------------------------------------------------------------------
// LayerNorm + ELU + present-mask.
// ---------------------------------------------------------------------------
__global__ void k_lnelu(const float* __restrict__ y, const float* __restrict__ ln_g,
                        const float* __restrict__ ln_b, const int* __restrict__ counts,
                        float* __restrict__ outp)
{
    const int row = blockIdx.x;
    const int k = row & 127;
    const int tid = threadIdx.x;

    float4 v = *reinterpret_cast<const float4*>(&y[(size_t)row * 1024 + tid * 4]);
    float s = v.x + v.y + v.z + v.w;
    float ss = v.x * v.x + v.y * v.y + v.z * v.z + v.w * v.w;
    #pragma unroll
    for (int off = 32; off; off >>= 1) { s += __shfl_xor(s, off); ss += __shfl_xor(ss, off); }

    __shared__ float sbuf[4], ssbuf[4];
    int wv = tid >> 6;
    if ((tid & 63) == 0) { sbuf[wv] = s; ssbuf[wv] = ss; }
    __syncthreads();
    s = sbuf[0] + sbuf[1] + sbuf[2] + sbuf[3];
    ss = ssbuf[0] + ssbuf[1] + ssbuf[2] + ssbuf[3];

    float mu = s * (1.f / 1024.f);
    float var = ss * (1.f / 1024.f) - mu * mu;
    float rstd = rsqrtf(var + 1e-5f);

    bool pres = false;
    #pragma unroll
    for (int bb = 0; bb < 8; ++bb) pres = pres || (counts[bb * NBLK + k] > 0);

    float4 g4 = *reinterpret_cast<const float4*>(&ln_g[tid * 4]);
    float4 b4 = *reinterpret_cast<const float4*>(&ln_b[tid * 4]);
    float vals[4] = {v.x, v.y, v.z, v.w};
    float gs[4] = {g4.x, g4.y, g4.z, g4.w};
    float bs[4] = {b4.x, b4.y, b4.z, b4.w};
    float4 o;
    float* op = &o.x;
    #pragma unroll
    for (int j = 0; j < 4; ++j) {
        float t = (vals[j] - mu) * rstd * gs[j] + bs[j];
        t = (t > 0.f) ? t : expm1f(t);
        op[j] = pres ? t : 0.f;
    }
    *reinterpret_cast<float4*>(&outp[(size_t)row * 1024 + tid * 4]) = o;
}

// ---------------------------------------------------------------------------
extern "C" void kernel_launch(void* const* d_in, const int* in_sizes, int n_in,
                              void* d_out, int out_size, void* d_ws, size_t ws_size,
                              hipStream_t stream)
{
    const float* x      = (const float*)d_in[0];
    const int*   ct     = (const int*)d_in[1];
    const int*   bids   = (const int*)d_in[2];
    const unsigned char* pad = (const unsigned char*)d_in[3];
    const float* W1     = (const float*)d_in[4];
    const float* b1     = (const float*)d_in[5];
    const float* W2     = (const float*)d_in[6];
    const float* b2     = (const float*)d_in[7];
    const float* ct_emb = (const float*)d_in[8];
    const float* Wp     = (const float*)d_in[9];
    const float* bp     = (const float*)d_in[10];
    const float* ln_g   = (const float*)d_in[11];
    const float* ln_b   = (const float*)d_in[12];
    float* outF = (float*)d_out;

    char* ws = (char*)d_ws;
    bf16s* w1t    = (bf16s*)(ws + 0);          //  1,048,576
    bf16s* wpt    = (bf16s*)(ws + 1048576);    //  2,097,152 -> 3,145,728
    float* gate   = (float*)(ws + 3145728);    //    131,072 -> 3,276,800
    float* part   = (float*)(ws + 3276800);    //    524,288 -> 3,801,088 (2 used)
    float* mblk   = (float*)(ws + 3801088);
    float* wscal  = (float*)(ws + 3805184);
    int*   counts = (int*)  (ws + 3809280);
    int*   lists  = (int*)  (ws + 3813376);    //  1,048,576 -> 4,861,952
    bf16s* pooled = (bf16s*)(ws + 4861952);    //  2,097,152 -> 6,959,104
    float* ybuf   = (float*)(ws + 6959104);    //  4,194,304 -> 11,153,408
    bf16s* xb     = (bf16s*)(ws + 11153408);   // 67,108,864 -> 78,262,272

    k_tcvt2<<<dim3(16, 24), 256, 0, stream>>>(W1, Wp, w1t, wpt);
    k_xcvt<<<2048, 256, 0, stream>>>(x, xb);
    k_gemm8<<<256, 512, 0, stream>>>(xb, w1t, b1, W2, part);
    k_blocks<<<1024, 64, 0, stream>>>(bids, pad, part, b2, gate, ct, ct_emb,
                                      counts, mblk, wscal, lists,
                                      outF + (size_t)8 * NBLK * HDIM);
    k_pool<<<1024, 256, 0, stream>>>(xb, gate, lists, counts, mblk, wscal, pooled);
    k_gemm2<<<256, 256, 0, stream>>>(pooled, wpt, bp, ybuf);
    k_lnelu<<<1024, 256, 0, stream>>>(ybuf, ln_g, ln_b, counts, outF);
}

// Round 12
// 129.123 us; speedup vs baseline: 1.5181x; 1.1173x over previous
//
#include <hip/hip_runtime.h>

// (B,N,H,NB,NCT) = (8,4096,1024,128,33), H/2 = 512
#define NTOK 4096
#define HDIM 1024
#define HHALF 512
#define NBLK 128
#define CAP 256

typedef __attribute__((ext_vector_type(8))) short short8;
typedef __attribute__((ext_vector_type(4))) float f32x4;
typedef short bf16s;

__device__ __forceinline__ short f2bf(float f) {
    unsigned u = __builtin_bit_cast(unsigned, f);
    u = (u + 0x7fffu + ((u >> 16) & 1u)) >> 16;   // RNE
    return (short)u;
}
__device__ __forceinline__ void gload_lds16(const void* g, void* l) {
    __builtin_amdgcn_global_load_lds(
        (const __attribute__((address_space(1))) unsigned int*)g,
        (__attribute__((address_space(3))) unsigned int*)l, 16, 0, 0);
}
__device__ __forceinline__ float fast_tanh(float v) {
    float e = __expf(2.0f * v);
    return 1.0f - 2.0f / (e + 1.0f);
}

// ---------------------------------------------------------------------------
// Tiled transpose+convert for both weights.
// ---------------------------------------------------------------------------
__global__ void k_tcvt2(const float* __restrict__ W1, const float* __restrict__ Wp,
                        bf16s* __restrict__ w1t, bf16s* __restrict__ wpt) {
    __shared__ float tile[64][65];
    const int by = blockIdx.y;
    const float* in = (by < 8) ? W1 : Wp;
    bf16s* out = (by < 8) ? w1t : wpt;
    const int Nc = (by < 8) ? HHALF : HDIM;
    const int n0 = ((by < 8) ? by : (by - 8)) * 64;
    const int k0 = blockIdx.x * 64;
    const int tx = threadIdx.x & 63, ty = threadIdx.x >> 6;
    #pragma unroll
    for (int i = 0; i < 16; ++i) {
        int r = ty + i * 4;
        tile[r][tx] = in[(size_t)(k0 + r) * Nc + n0 + tx];
    }
    __syncthreads();
    #pragma unroll
    for (int i = 0; i < 16; ++i) {
        int r = ty + i * 4;
        out[(size_t)(n0 + r) * 1024 + k0 + tx] = f2bf(tile[tx][r]);
    }
}

// ---------------------------------------------------------------------------
// Gate GEMM — R11 8-phase 256x256 skeleton, with A consumed DIRECTLY from
// f32 x (no xcvt pass, no xb buffer):
//   A path: coalesced float4 loads (issued 2 phases ahead, reg-double-buffered
//   RA/RB) -> 8x f2bf -> ds_write_b128 into the SAME bf16 LDS layout as R11.
//   LDS stays 64 KB; fragment reads stay bf16; B stays on counted-vmcnt gll.
// vmcnt FIFO per tile (issue order): [B#1, B#2, A-f32 x4] -> vmcnt(4) at each
// tile-start certifies B(t) complete while A(t+1) regs stay in flight; the
// compiler's auto-wait for A regs sits BEFORE the next B issue (no drain).
// ---------------------------------------------------------------------------
__global__ __launch_bounds__(512, 1) void k_gemm8f(
    const float* __restrict__ x, const bf16s* __restrict__ w1t,
    const float* __restrict__ b1, const float* __restrict__ w2,
    float* __restrict__ partial)
{
    __shared__ alignas(16) bf16s As[2][256 * 32];
    __shared__ alignas(16) bf16s Bs[2][256 * 32];

    const int tid = threadIdx.x;
    const int lane = tid & 63;
    const int wv = tid >> 6;           // 0..7
    const int wm = wv >> 2;            // 0..1
    const int wn = wv & 3;             // 0..3
    const int phys = blockIdx.x;
    const int logical = (phys & 7) * 32 + (phys >> 3);  // 256 = 8*32 bijective
    const int row0 = (logical >> 1) * 256;
    const int ctile = logical & 1;
    const int col0 = ctile * 256;
    const int c0 = lane & 15, khalf = lane >> 4;

    // staging geometry (identical layout to R11's gll scheme)
    const int sj = (lane & 3) ^ ((lane >> 3) & 3);
    const int arow0 = ((wv & 4) ? 128 : 0) + (wv & 3) * 16 + (lane >> 2);
    const float* aF0 = &x[(size_t)(row0 + arow0) * HDIM + sj * 8];  // f32 src
    const float* aF1 = aF0 + (size_t)64 * HDIM;
    const int adst0 = (((wv & 4) ? 128 : 0) + (wv & 3) * 16) * 32 + lane * 8;
    const int adst1 = adst0 + 64 * 32;
    const int brow0 = wv * 16 + (lane >> 2);
    const bf16s* bS0 = &w1t[(size_t)(col0 + brow0) * HDIM + sj * 8];
    const bf16s* bS1 = bS0 + (size_t)128 * HDIM;
    const int bdst0 = (wv * 16) * 32 + lane * 8;
    const int bdst1 = bdst0 + 128 * 32;

    // fragment reads (R11-verified)
    const int ch8 = (khalf ^ ((c0 >> 1) & 3)) * 8;
    const int arA = (wm * 128 + c0) * 32 + ch8;   // + mf*512
    const int brB = (wn * 64 + c0) * 32 + ch8;    // + nf*512

    f32x4 acc[8][4] = {};
    short8 av[4], bvv[4];

#define MFMA16(MB)                                                            \
    __builtin_amdgcn_s_setprio(1);                                           \
    _Pragma("unroll")                                                         \
    for (int n = 0; n < 4; ++n)                                               \
        _Pragma("unroll")                                                     \
        for (int m = 0; m < 4; ++m)                                           \
            acc[(MB) + m][n] =                                                \
                __builtin_amdgcn_mfma_f32_16x16x32_bf16(av[m], bvv[n],        \
                                                        acc[(MB) + m][n], 0, 0, 0); \
    __builtin_amdgcn_s_setprio(0);

#define CVTWR(U0, U1, DST, BUF) do {                                          \
        short h_[8] = {f2bf((U0).x), f2bf((U0).y), f2bf((U0).z), f2bf((U0).w),\
                       f2bf((U1).x), f2bf((U1).y), f2bf((U1).z), f2bf((U1).w)};\
        *reinterpret_cast<int4*>(&As[BUF][DST]) =                             \
            *reinterpret_cast<const int4*>(h_);                               \
    } while (0)

    // ---- prologue ----
    // A(0): load f32, cvt, ds_write buf0 (compiler vmcnt handles reg deps)
    {
        float4 p0 = *reinterpret_cast<const float4*>(aF0);
        float4 p1 = *reinterpret_cast<const float4*>(aF0 + 4);
        float4 p2 = *reinterpret_cast<const float4*>(aF1);
        float4 p3 = *reinterpret_cast<const float4*>(aF1 + 4);
        CVTWR(p0, p1, adst0, 0);
        CVTWR(p2, p3, adst1, 0);
    }
    // B(0): 2 gll -> buf0  (FIFO: these precede RA loads)
    gload_lds16(bS0, &Bs[0][bdst0]);
    gload_lds16(bS1, &Bs[0][bdst1]);
    // RA = A(1) f32 (consumed during tile 0)
    float4 ra0 = *reinterpret_cast<const float4*>(aF0 + 32);
    float4 ra1 = *reinterpret_cast<const float4*>(aF0 + 36);
    float4 ra2 = *reinterpret_cast<const float4*>(aF1 + 32);
    float4 ra3 = *reinterpret_cast<const float4*>(aF1 + 36);
    float4 rb0, rb1, rb2, rb3;
    asm volatile("s_waitcnt lgkmcnt(0)" ::: "memory");   // A(0) writes done

    for (int it = 0; it < 16; ++it) {
        const int ka = 2 * it, kb = ka + 1;

        // ================= tile ka (buf0); R holds A(ka+1) = RA ============
        // --- P0 (m-half 0) ---
        asm volatile("s_waitcnt vmcnt(4)" ::: "memory");  // B(ka) done; RA in flight
        __builtin_amdgcn_s_barrier();
        #pragma unroll
        for (int m = 0; m < 4; ++m)
            av[m] = *reinterpret_cast<const short8*>(&As[0][arA + m * 512]);
        #pragma unroll
        for (int n = 0; n < 4; ++n)
            bvv[n] = *reinterpret_cast<const short8*>(&Bs[0][brB + n * 512]);
        CVTWR(ra0, ra1, adst0, 1);                         // A(ka+1) h0 -> buf1
        gload_lds16(bS0 + (ka + 1) * 32, &Bs[1][bdst0]);   // B(ka+1)#1
        asm volatile("s_waitcnt lgkmcnt(0)" ::: "memory");
        __builtin_amdgcn_sched_barrier(0);
        MFMA16(0)
        __builtin_amdgcn_s_barrier();
        // --- P1 (m-half 1) ---
        #pragma unroll
        for (int m = 0; m < 4; ++m)
            av[m] = *reinterpret_cast<const short8*>(&As[0][arA + (4 + m) * 512]);
        CVTWR(ra2, ra3, adst1, 1);                         // A(ka+1) h1 -> buf1
        gload_lds16(bS1 + (ka + 1) * 32, &Bs[1][bdst1]);   // B(ka+1)#2
        if (ka < 30) {                                     // RB = A(ka+2)
            rb0 = *reinterpret_cast<const float4*>(aF0 + (ka + 2) * 32);
            rb1 = *reinterpret_cast<const float4*>(aF0 + (ka + 2) * 32 + 4);
            rb2 = *reinterpret_cast<const float4*>(aF1 + (ka + 2) * 32);
            rb3 = *reinterpret_cast<const float4*>(aF1 + (ka + 2) * 32 + 4);
        }
        __builtin_amdgcn_s_barrier();
        asm volatile("s_waitcnt lgkmcnt(0)" ::: "memory");
        __builtin_amdgcn_sched_barrier(0);
        MFMA16(4)
        __builtin_amdgcn_s_barrier();

        // ================= tile kb (buf1); R holds A(kb+1) = RB ============
        const bool nl = (kb < 31);
        // --- P0 ---
        if (nl) {
            asm volatile("s_waitcnt vmcnt(4)" ::: "memory");
        } else {
            asm volatile("s_waitcnt vmcnt(0)" ::: "memory");
        }
        __builtin_amdgcn_s_barrier();
        #pragma unroll
        for (int m = 0; m < 4; ++m)
            av[m] = *reinterpret_cast<const short8*>(&As[1][arA + m * 512]);
        #pragma unroll
        for (int n = 0; n < 4; ++n)
            bvv[n] = *reinterpret_cast<const short8*>(&Bs[1][brB + n * 512]);
        if (nl) {
            CVTWR(rb0, rb1, adst0, 0);                       // A(kb+1) h0 -> buf0
            gload_lds16(bS0 + (kb + 1) * 32, &Bs[0][bdst0]); // B(kb+1)#1
        }
        asm volatile("s_waitcnt lgkmcnt(0)" ::: "memory");
        __builtin_amdgcn_sched_barrier(0);
        MFMA16(0)
        __builtin_amdgcn_s_barrier();
        // --- P1 ---
        #pragma unroll
        for (int m = 0; m < 4; ++m)
            av[m] = *reinterpret_cast<const short8*>(&As[1][arA + (4 + m) * 512]);
        if (nl) {
            CVTWR(rb2, rb3, adst1, 0);                       // A(kb+1) h1 -> buf0
            gload_lds16(bS1 + (kb + 1) * 32, &Bs[0][bdst1]); // B(kb+1)#2
        }
        if (kb < 30) {                                       // RA = A(kb+2)
            ra0 = *reinterpret_cast<const float4*>(aF0 + (kb + 2) * 32);
            ra1 = *reinterpret_cast<const float4*>(aF0 + (kb + 2) * 32 + 4);
            ra2 = *reinterpret_cast<const float4*>(aF1 + (kb + 2) * 32);
            ra3 = *reinterpret_cast<const float4*>(aF1 + (kb + 2) * 32 + 4);
        }
        __builtin_amdgcn_s_barrier();
        asm volatile("s_waitcnt lgkmcnt(0)" ::: "memory");
        __builtin_amdgcn_sched_barrier(0);
        MFMA16(4)
        __builtin_amdgcn_s_barrier();
    }
#undef MFMA16
#undef CVTWR

    // epilogue: per-row dot of tanh(h)*W2 over this wave's 64 cols;
    // gp[4][256] aliased into As (all LDS ops drained by final lgkm+barrier).
    float* gp = reinterpret_cast<float*>(&As[0][0]);
    float b1v[4], w2v[4];
    #pragma unroll
    for (int nf = 0; nf < 4; ++nf) {
        int gc = col0 + wn * 64 + nf * 16 + c0;
        b1v[nf] = b1[gc];
        w2v[nf] = w2[gc];
    }
    #pragma unroll
    for (int mf = 0; mf < 8; ++mf) {
        #pragma unroll
        for (int reg = 0; reg < 4; ++reg) {
            float s = 0.f;
            #pragma unroll
            for (int nf = 0; nf < 4; ++nf)
                s += fast_tanh(acc[mf][nf][reg] + b1v[nf]) * w2v[nf];
            s += __shfl_xor(s, 1); s += __shfl_xor(s, 2);
            s += __shfl_xor(s, 4); s += __shfl_xor(s, 8);
            if (c0 == 0)
                gp[wn * 256 + wm * 128 + mf * 16 + khalf * 4 + reg] = s;
        }
    }
    __syncthreads();
    if (tid < 256)
        partial[(size_t)ctile * 32768 + row0 + tid] =
            gp[tid] + gp[256 + tid] + gp[512 + tid] + gp[768 + tid];
}

// ---------------------------------------------------------------------------
// Single-pass per-(b,block): sums the 2 gate partials for member tokens,
// online-softmax stats, ordered lists.
// ---------------------------------------------------------------------------
__global__ void k_blocks(const int* __restrict__ block_ids, const unsigned char* __restrict__ pad,
                         const float* __restrict__ part, const float* __restrict__ b2,
                         float* __restrict__ gate, const int* __restrict__ ct,
                         const float* __restrict__ ct_emb,
                         int* __restrict__ counts, float* __restrict__ mblk,
                         float* __restrict__ wscale, int* __restrict__ lists,
                         float* __restrict__ out_hasb)
{
    const int blk = blockIdx.x;
    const int b = blk >> 7, k = blk & 127;
    const int lane = threadIdx.x;
    const int base = b * NTOK;
    const int lbase = blk * CAP;
    const unsigned long long ltmask = (1ull << lane) - 1ull;
    const float b2v = b2[0];

    float m = -__builtin_inff();
    float s = 0.f;
    int pos = 0;
    for (int t0 = 0; t0 < NTOK; t0 += 64) {
        int t = t0 + lane;
        bool mt = (block_ids[base + t] == k) && (pad[base + t] == 0);
        unsigned long long mask = __ballot(mt);
        if (mt) {
            int r = base + t;
            float g = part[r] + part[32768 + r] + b2v;
            gate[r] = g;   // each valid token belongs to exactly one block
            int my = pos + __popcll(mask & ltmask);
            if (my < CAP) lists[lbase + my] = t;
            float mn = fmaxf(m, g);
            s = s * __expf(m - mn) + __expf(g - mn);
            m = mn;
        }
        pos += __popcll(mask);
    }
    #pragma unroll
    for (int off = 1; off < 64; off <<= 1) {
        float om = __shfl_xor(m, off);
        float os = __shfl_xor(s, off);
        float mn = fmaxf(m, om);
        float sa = (m == -__builtin_inff()) ? 0.f : s * __expf(m - mn);
        float sb = (om == -__builtin_inff()) ? 0.f : os * __expf(om - mn);
        s = sa + sb;
        m = mn;
    }
    if (lane == 0) {
        counts[blk] = pos;
        mblk[blk] = (pos > 0) ? m : 0.f;
        float mod = 1.0f + 0.1f * ct_emb[ct[b] * NBLK + k];
        wscale[blk] = (pos > 0 && s > 0.f) ? (mod / fmaxf(s, 1e-30f)) : 0.f;
        out_hasb[blk] = (pos > 0) ? 1.f : 0.f;
    }
}

// ---------------------------------------------------------------------------
// Pooling from f32 x: pooled[b,k,:] = wscale * sum_n exp(gate[n]-m) * x[b,n,:]
// ---------------------------------------------------------------------------
__global__ void k_pool(const float* __restrict__ x, const float* __restrict__ gate,
                       const int* __restrict__ lists, const int* __restrict__ counts,
                       const float* __restrict__ mblk, const float* __restrict__ wscale,
                       bf16s* __restrict__ pooled)
{
    const int blk = blockIdx.x;
    const int b = blk >> 7;
    const int tid = threadIdx.x;
    const int base = b * NTOK;
    const int cnt = min(counts[blk], CAP);
    const int lbase = blk * CAP;
    const float m = mblk[blk], ws = wscale[blk];

    float4 acc = {0.f, 0.f, 0.f, 0.f};
    for (int i = 0; i < cnt; ++i) {
        int n = lists[lbase + i];
        float w = __expf(gate[base + n] - m);
        float4 xv = *reinterpret_cast<const float4*>(&x[(size_t)(base + n) * HDIM + tid * 4]);
        acc.x += w * xv.x; acc.y += w * xv.y; acc.z += w * xv.z; acc.w += w * xv.w;
    }
    short o[4] = {f2bf(acc.x * ws), f2bf(acc.y * ws), f2bf(acc.z * ws), f2bf(acc.w * ws)};
    *reinterpret_cast<int2*>(&pooled[(size_t)blk * HDIM + tid * 4]) =
        *reinterpret_cast<const int2*>(o);
}

// ---------------------------------------------------------------------------
// GEMM2: y = pooled @ Wp + bp. 1024^3. 64x64 tiles, 4 waves, dbuf + gll,
// counted-vmcnt schedule.
// ---------------------------------------------------------------------------
__global__ __launch_bounds__(256) void k_gemm2(
    const bf16s* __restrict__ pooled, const bf16s* __restrict__ wpt,
    const float* __restrict__ bp, float* __restrict__ y)
{
    __shared__ alignas(16) bf16s As[2][64 * 32];
    __shared__ alignas(16) bf16s Bs[2][64 * 32];
    const int tid = threadIdx.x;
    const int lane = tid & 63;
    const int wv = tid >> 6;
    const int wr = wv >> 1, wc = wv & 1;
    const int row0 = (blockIdx.x >> 4) * 64, col0 = (blockIdx.x & 15) * 64;
    const int c0 = lane & 15, khalf = lane >> 4;

    const int sr = wv * 16 + (lane >> 2);
    const int sj = (lane & 3) ^ ((sr >> 1) & 3);
    const int sdst = (wv * 16) * 32 + lane * 8;
    const bf16s* srcA = &pooled[(size_t)(row0 + sr) * 1024 + sj * 8];
    const bf16s* srcB = &wpt[(size_t)(col0 + sr) * 1024 + sj * 8];

    f32x4 acc[2][2] = {};

    gload_lds16(srcA, &As[0][sdst]);
    gload_lds16(srcB, &Bs[0][sdst]);

    for (int t = 0; t < 32; ++t) {
        const int cur = t & 1;
        if (t < 31) {
            gload_lds16(srcA + (t + 1) * 32, &As[cur ^ 1][sdst]);
            gload_lds16(srcB + (t + 1) * 32, &Bs[cur ^ 1][sdst]);
            asm volatile("s_waitcnt vmcnt(2)" ::: "memory");
        } else {
            asm volatile("s_waitcnt vmcnt(0)" ::: "memory");
        }
        __builtin_amdgcn_s_barrier();
        __builtin_amdgcn_sched_barrier(0);
        #pragma unroll
        for (int mf = 0; mf < 2; ++mf) {
            int ra = wr * 32 + mf * 16 + c0;
            short8 av = *reinterpret_cast<const short8*>(
                &As[cur][ra * 32 + ((khalf ^ ((ra >> 1) & 3)) * 8)]);
            #pragma unroll
            for (int nf = 0; nf < 2; ++nf) {
                int rb = wc * 32 + nf * 16 + c0;
                short8 bv = *reinterpret_cast<const short8*>(
                    &Bs[cur][rb * 32 + ((khalf ^ ((rb >> 1) & 3)) * 8)]);
                acc[mf][nf] = __builtin_amdgcn_mfma_f32_16x16x32_bf16(av, bv, acc[mf][nf], 0, 0, 0);
            }
        }
        asm volatile("s_waitcnt lgkmcnt(0)" ::: "memory");
        __builtin_amdgcn_sched_barrier(0);
        __builtin_amdgcn_s_barrier();
    }
    #pragma unroll
    for (int mf = 0; mf < 2; ++mf)
        #pragma unroll
        for (int nf = 0; nf < 2; ++nf)
            #pragma unroll
            for (int reg = 0; reg < 4; ++reg) {
                int grow = row0 + wr * 32 + mf * 16 + khalf * 4 + reg;
                int gcol = col0 + wc * 32 + nf * 16 + c0;
                y[(size_t)grow * 1024 + gcol] = acc[mf][nf][reg] + bp[gcol];
            }
}

// ---------------------------------------------------------------------------
// LayerNorm + ELU + present-mask.
// ---------------------------------------------------------------------------
__global__ void k_lnelu(const float* __restrict__ y, const float* __restrict__ ln_g,
                        const float* __restrict__ ln_b, const int* __restrict__ counts,
                        float* __restrict__ outp)
{
    const int row = blockIdx.x;
    const int k = row & 127;
    const int tid = threadIdx.x;

    float4 v = *reinterpret_cast<const float4*>(&y[(size_t)row * 1024 + tid * 4]);
    float s = v.x + v.y + v.z + v.w;
    float ss = v.x * v.x + v.y * v.y + v.z * v.z + v.w * v.w;
    #pragma unroll
    for (int off = 32; off; off >>= 1) { s += __shfl_xor(s, off); ss += __shfl_xor(ss, off); }

    __shared__ float sbuf[4], ssbuf[4];
    int wv = tid >> 6;
    if ((tid & 63) == 0) { sbuf[wv] = s; ssbuf[wv] = ss; }
    __syncthreads();
    s = sbuf[0] + sbuf[1] + sbuf[2] + sbuf[3];
    ss = ssbuf[0] + ssbuf[1] + ssbuf[2] + ssbuf[3];

    float mu = s * (1.f / 1024.f);
    float var = ss * (1.f / 1024.f) - mu * mu;
    float rstd = rsqrtf(var + 1e-5f);

    bool pres = false;
    #pragma unroll
    for (int bb = 0; bb < 8; ++bb) pres = pres || (counts[bb * NBLK + k] > 0);

    float4 g4 = *reinterpret_cast<const float4*>(&ln_g[tid * 4]);
    float4 b4 = *reinterpret_cast<const float4*>(&ln_b[tid * 4]);
    float vals[4] = {v.x, v.y, v.z, v.w};
    float gs[4] = {g4.x, g4.y, g4.z, g4.w};
    float bs[4] = {b4.x, b4.y, b4.z, b4.w};
    float4 o;
    float* op = &o.x;
    #pragma unroll
    for (int j = 0; j < 4; ++j) {
        float t = (vals[j] - mu) * rstd * gs[j] + bs[j];
        t = (t > 0.f) ? t : expm1f(t);
        op[j] = pres ? t : 0.f;
    }
    *reinterpret_cast<float4*>(&outp[(size_t)row * 1024 + tid * 4]) = o;
}

// ---------------------------------------------------------------------------
extern "C" void kernel_launch(void* const* d_in, const int* in_sizes, int n_in,
                              void* d_out, int out_size, void* d_ws, size_t ws_size,
                              hipStream_t stream)
{
    const float* x      = (const float*)d_in[0];
    const int*   ct     = (const int*)d_in[1];
    const int*   bids   = (const int*)d_in[2];
    const unsigned char* pad = (const unsigned char*)d_in[3];
    const float* W1     = (const float*)d_in[4];
    const float* b1     = (const float*)d_in[5];
    const float* W2     = (const float*)d_in[6];
    const float* b2     = (const float*)d_in[7];
    const float* ct_emb = (const float*)d_in[8];
    const float* Wp     = (const float*)d_in[9];
    const float* bp     = (const float*)d_in[10];
    const float* ln_g   = (const float*)d_in[11];
    const float* ln_b   = (const float*)d_in[12];
    float* outF = (float*)d_out;

    char* ws = (char*)d_ws;
    bf16s* w1t    = (bf16s*)(ws + 0);          //  1,048,576
    bf16s* wpt    = (bf16s*)(ws + 1048576);    //  2,097,152 -> 3,145,728
    float* gate   = (float*)(ws + 3145728);    //    131,072 -> 3,276,800
    float* part   = (float*)(ws + 3276800);    //    524,288 -> 3,801,088 (2 used)
    float* mblk   = (float*)(ws + 3801088);
    float* wscal  = (float*)(ws + 3805184);
    int*   counts = (int*)  (ws + 3809280);
    int*   lists  = (int*)  (ws + 3813376);    //  1,048,576 -> 4,861,952
    bf16s* pooled = (bf16s*)(ws + 4861952);    //  2,097,152 -> 6,959,104
    float* ybuf   = (float*)(ws + 6959104);    //  4,194,304 -> 11,153,408

    k_tcvt2<<<dim3(16, 24), 256, 0, stream>>>(W1, Wp, w1t, wpt);
    k_gemm8f<<<256, 512, 0, stream>>>(x, w1t, b1, W2, part);
    k_blocks<<<1024, 64, 0, stream>>>(bids, pad, part, b2, gate, ct, ct_emb,
                                      counts, mblk, wscal, lists,
                                      outF + (size_t)8 * NBLK * HDIM);
    k_pool<<<1024, 256, 0, stream>>>(x, gate, lists, counts, mblk, wscal, pooled);
    k_gemm2<<<256, 256, 0, stream>>>(pooled, wpt, bp, ybuf);
    k_lnelu<<<1024, 256, 0, stream>>>(ybuf, ln_g, ln_b, counts, outF);
}

// Round 13
// 125.579 us; speedup vs baseline: 1.5609x; 1.0282x over previous
//
#include <hip/hip_runtime.h>

// (B,N,H,NB,NCT) = (8,4096,1024,128,33), H/2 = 512
#define NTOK 4096
#define HDIM 1024
#define HHALF 512
#define NBLK 128
#define CAP 256

typedef __attribute__((ext_vector_type(8))) short short8;
typedef __attribute__((ext_vector_type(4))) float f32x4;
typedef short bf16s;

__device__ __forceinline__ short f2bf(float f) {
    unsigned u = __builtin_bit_cast(unsigned, f);
    u = (u + 0x7fffu + ((u >> 16) & 1u)) >> 16;   // RNE
    return (short)u;
}
__device__ __forceinline__ void gload_lds16(const void* g, void* l) {
    __builtin_amdgcn_global_load_lds(
        (const __attribute__((address_space(1))) unsigned int*)g,
        (__attribute__((address_space(3))) unsigned int*)l, 16, 0, 0);
}
__device__ __forceinline__ float fast_tanh(float v) {
    float e = __expf(2.0f * v);
    return 1.0f - 2.0f / (e + 1.0f);
}

// ---------------------------------------------------------------------------
// Tiled transpose+convert for both weights.
// ---------------------------------------------------------------------------
__global__ void k_tcvt2(const float* __restrict__ W1, const float* __restrict__ Wp,
                        bf16s* __restrict__ w1t, bf16s* __restrict__ wpt) {
    __shared__ float tile[64][65];
    const int by = blockIdx.y;
    const float* in = (by < 8) ? W1 : Wp;
    bf16s* out = (by < 8) ? w1t : wpt;
    const int Nc = (by < 8) ? HHALF : HDIM;
    const int n0 = ((by < 8) ? by : (by - 8)) * 64;
    const int k0 = blockIdx.x * 64;
    const int tx = threadIdx.x & 63, ty = threadIdx.x >> 6;
    #pragma unroll
    for (int i = 0; i < 16; ++i) {
        int r = ty + i * 4;
        tile[r][tx] = in[(size_t)(k0 + r) * Nc + n0 + tx];
    }
    __syncthreads();
    #pragma unroll
    for (int i = 0; i < 16; ++i) {
        int r = ty + i * 4;
        out[(size_t)(n0 + r) * 1024 + k0 + tx] = f2bf(tile[tx][r]);
    }
}

// ---------------------------------------------------------------------------
// Gate GEMM v13: 128x256 tile, BK=32, 256 thr = 4 waves (1m x 4n),
// wave-out 128x64 = acc[8][4]. 48 KB LDS + 240 regs/wave -> 2 wgs/CU
// (cross-wg overlap hides barrier/vmcnt stalls; m114 mechanism).
// ONE barrier per K-iter (32 total). Counted-vmcnt by construction:
//   iter t FIFO (oldest->newest): [B(t)x4, Af32(t+1)x4]
//   issue B(t+1)x4           -> [B(t)4, Af32(t+1)4, B(t+1)4]
//   CVTWR uses Af32(t+1)     -> compiler waits vmcnt(4): retires B(t)+Af32(t+1),
//                               keeps B(t+1) in flight (never drains pipeline)
//   issue Af32(t+2)          -> steady state [B(t+1)4, Af32(t+2)4]
//   lgkmcnt(0)+barrier certifies: B(t) gll writes (vmcnt'd above, all waves)
//   and A(t) CVTWR writes (iter t-1) -> compute tile t.
// A f32->bf16 inline (no xcvt pass). Swizzle keys R12-verified:
//   LDS chunk slot s holds source chunk s^((row>>1)&3); reads XOR same key.
// ---------------------------------------------------------------------------
__global__ __launch_bounds__(256, 2) void k_gemmv(
    const float* __restrict__ x, const bf16s* __restrict__ w1t,
    const float* __restrict__ b1, const float* __restrict__ w2,
    float* __restrict__ partial)
{
    __shared__ alignas(16) bf16s As[2][128 * 32];   //  16 KB
    __shared__ alignas(16) bf16s Bs[2][256 * 32];   //  32 KB

    const int tid = threadIdx.x;
    const int lane = tid & 63;
    const int wn = tid >> 6;                        // 0..3 (col group)
    const int phys = blockIdx.x;
    const int logical = (phys & 7) * 64 + (phys >> 3);  // 512 = 8*64 bijective
    const int rp = logical >> 1;                    // 0..255
    const int ctile = logical & 1;
    const int row0 = rp * 128;
    const int col0 = ctile * 256;
    const int c0 = lane & 15, khalf = lane >> 4;

    // ---- A staging (f32 -> regs -> cvt -> ds_write, swizzled dest) ----
    const int ar = tid >> 1, ah = tid & 1;          // row 0..127, 16-col half
    const float* aF = &x[(size_t)(row0 + ar) * HDIM + ah * 16];
    const int akey = (ar >> 1) & 3;
    const int aslot0 = ((2 * ah) ^ akey) * 8;       // dest chunk slots (shorts)
    const int aslot1 = ((2 * ah + 1) ^ akey) * 8;
    const int arow32 = ar * 32;

    // ---- B staging (gll, pre-swizzled source) ----
    const int sj = (lane & 3) ^ ((lane >> 3) & 3);
    const bf16s* bS[4];
    int bdst[4];
    #pragma unroll
    for (int q = 0; q < 4; ++q) {
        int rb = wn * 64 + q * 16 + (lane >> 2);
        bS[q] = &w1t[(size_t)(col0 + rb) * HDIM + sj * 8];
        bdst[q] = (wn * 64 + q * 16) * 32 + lane * 8;
    }

    // ---- fragment read offsets ----
    const int fkey = (c0 >> 1) & 3;                 // == ((mf*16+c0)>>1)&3
    const int ach = (khalf ^ fkey) * 8;
    const int arA = c0 * 32 + ach;                  // + mf*16*32
    const int brB = (wn * 64 + c0) * 32 + ach;      // + nf*16*32 (same key math)

    f32x4 acc[8][4] = {};
    float4 rA0, rA1, rA2, rA3;

#define LOAD_RA(T) do {                                               \
        rA0 = *reinterpret_cast<const float4*>(aF + (T) * 32);        \
        rA1 = *reinterpret_cast<const float4*>(aF + (T) * 32 + 4);    \
        rA2 = *reinterpret_cast<const float4*>(aF + (T) * 32 + 8);    \
        rA3 = *reinterpret_cast<const float4*>(aF + (T) * 32 + 12);   \
    } while (0)
#define CVTWR(BUF) do {                                               \
        short h_[16] = {f2bf(rA0.x), f2bf(rA0.y), f2bf(rA0.z), f2bf(rA0.w), \
                        f2bf(rA1.x), f2bf(rA1.y), f2bf(rA1.z), f2bf(rA1.w), \
                        f2bf(rA2.x), f2bf(rA2.y), f2bf(rA2.z), f2bf(rA2.w), \
                        f2bf(rA3.x), f2bf(rA3.y), f2bf(rA3.z), f2bf(rA3.w)};\
        *reinterpret_cast<int4*>(&As[BUF][arow32 + aslot0]) =         \
            *reinterpret_cast<const int4*>(&h_[0]);                   \
        *reinterpret_cast<int4*>(&As[BUF][arow32 + aslot1]) =         \
            *reinterpret_cast<const int4*>(&h_[8]);                   \
    } while (0)

    // ---- prologue: A(0)+B(0) -> buf0; rA = A(1) ----
    LOAD_RA(0);
    CVTWR(0);
    #pragma unroll
    for (int q = 0; q < 4; ++q)
        gload_lds16(bS[q], &Bs[0][bdst[q]]);
    LOAD_RA(1);

    for (int t = 0; t < 32; ++t) {
        const int c = t & 1;
        if (t < 31) {
            // stage tile t+1 into buf c^1 (certified dead: read at t-1, barrier since)
            #pragma unroll
            for (int q = 0; q < 4; ++q)
                gload_lds16(bS[q] + (t + 1) * 32, &Bs[c ^ 1][bdst[q]]);
            __builtin_amdgcn_sched_barrier(0);   // pin gll-before-CVTWR (keeps B(t+1) newest)
            CVTWR(c ^ 1);                        // implicit vmcnt(4): retires B(t)+Af32(t+1)
            if (t < 30) LOAD_RA(t + 2);
        } else {
            asm volatile("s_waitcnt vmcnt(0)" ::: "memory");
        }
        asm volatile("s_waitcnt lgkmcnt(0)" ::: "memory");  // A(t) (+just-issued) writes done
        __builtin_amdgcn_sched_barrier(0);
        __builtin_amdgcn_s_barrier();                       // tile t certified for all waves

        short8 av[8], bvv[4];
        #pragma unroll
        for (int mf = 0; mf < 8; ++mf)
            av[mf] = *reinterpret_cast<const short8*>(&As[c][arA + mf * 512]);
        #pragma unroll
        for (int nf = 0; nf < 4; ++nf)
            bvv[nf] = *reinterpret_cast<const short8*>(&Bs[c][brB + nf * 512]);
        asm volatile("s_waitcnt lgkmcnt(0)" ::: "memory");
        __builtin_amdgcn_sched_barrier(0);

        __builtin_amdgcn_s_setprio(1);
        #pragma unroll
        for (int nf = 0; nf < 4; ++nf)
            #pragma unroll
            for (int mf = 0; mf < 8; ++mf)
                acc[mf][nf] = __builtin_amdgcn_mfma_f32_16x16x32_bf16(av[mf], bvv[nf], acc[mf][nf], 0, 0, 0);
        __builtin_amdgcn_s_setprio(0);
        // no trailing barrier: my ds_reads are consumed before my next-iter barrier
        // arrival; writes to buf c resume only after TWO more top barriers (t+2).
    }
#undef LOAD_RA
#undef CVTWR

    // epilogue: per-row dot of tanh(h)*W2 over this wave's 64 cols.
    // gp[4][128] aliased into As (all LDS traffic drained: lgkm+barrier path).
    __syncthreads();
    float* gp = reinterpret_cast<float*>(&As[0][0]);
    float b1v[4], w2v[4];
    #pragma unroll
    for (int nf = 0; nf < 4; ++nf) {
        int gc = col0 + wn * 64 + nf * 16 + c0;
        b1v[nf] = b1[gc];
        w2v[nf] = w2[gc];
    }
    #pragma unroll
    for (int mf = 0; mf < 8; ++mf) {
        #pragma unroll
        for (int reg = 0; reg < 4; ++reg) {
            float s = 0.f;
            #pragma unroll
            for (int nf = 0; nf < 4; ++nf)
                s += fast_tanh(acc[mf][nf][reg] + b1v[nf]) * w2v[nf];
            s += __shfl_xor(s, 1); s += __shfl_xor(s, 2);
            s += __shfl_xor(s, 4); s += __shfl_xor(s, 8);
            if (c0 == 0) gp[wn * 128 + mf * 16 + khalf * 4 + reg] = s;
        }
    }
    __syncthreads();
    if (tid < 128)
        partial[(size_t)ctile * 32768 + row0 + tid] =
            gp[tid] + gp[128 + tid] + gp[256 + tid] + gp[384 + tid];
}

// ---------------------------------------------------------------------------
// Single-pass per-(b,block): sums the 2 gate partials for member tokens,
// online-softmax stats, ordered lists.
// ---------------------------------------------------------------------------
__global__ void k_blocks(const int* __restrict__ block_ids, const unsigned char* __restrict__ pad,
                         const float* __restrict__ part, const float* __restrict__ b2,
                         float* __restrict__ gate, const int* __restrict__ ct,
                         const float* __restrict__ ct_emb,
                         int* __restrict__ counts, float* __restrict__ mblk,
                         float* __restrict__ wscale, int* __restrict__ lists,
                         float* __restrict__ out_hasb)
{
    const int blk = blockIdx.x;
    const int b = blk >> 7, k = blk & 127;
    const int lane = threadIdx.x;
    const int base = b * NTOK;
    const int lbase = blk * CAP;
    const unsigned long long ltmask = (1ull << lane) - 1ull;
    const float b2v = b2[0];

    float m = -__builtin_inff();
    float s = 0.f;
    int pos = 0;
    for (int t0 = 0; t0 < NTOK; t0 += 64) {
        int t = t0 + lane;
        bool mt = (block_ids[base + t] == k) && (pad[base + t] == 0);
        unsigned long long mask = __ballot(mt);
        if (mt) {
            int r = base + t;
            float g = part[r] + part[32768 + r] + b2v;
            gate[r] = g;   // each valid token belongs to exactly one block
            int my = pos + __popcll(mask & ltmask);
            if (my < CAP) lists[lbase + my] = t;
            float mn = fmaxf(m, g);
            s = s * __expf(m - mn) + __expf(g - mn);
            m = mn;
        }
        pos += __popcll(mask);
    }
    #pragma unroll
    for (int off = 1; off < 64; off <<= 1) {
        float om = __shfl_xor(m, off);
        float os = __shfl_xor(s, off);
        float mn = fmaxf(m, om);
        float sa = (m == -__builtin_inff()) ? 0.f : s * __expf(m - mn);
        float sb = (om == -__builtin_inff()) ? 0.f : os * __expf(om - mn);
        s = sa + sb;
        m = mn;
    }
    if (lane == 0) {
        counts[blk] = pos;
        mblk[blk] = (pos > 0) ? m : 0.f;
        float mod = 1.0f + 0.1f * ct_emb[ct[b] * NBLK + k];
        wscale[blk] = (pos > 0 && s > 0.f) ? (mod / fmaxf(s, 1e-30f)) : 0.f;
        out_hasb[blk] = (pos > 0) ? 1.f : 0.f;
    }
}

// ---------------------------------------------------------------------------
// Pooling from f32 x (L3-resident; measured ≈ bf16 speed).
// ---------------------------------------------------------------------------
__global__ void k_pool(const float* __restrict__ x, const float* __restrict__ gate,
                       const int* __restrict__ lists, const int* __restrict__ counts,
                       const float* __restrict__ mblk, const float* __restrict__ wscale,
                       bf16s* __restrict__ pooled)
{
    const int blk = blockIdx.x;
    const int b = blk >> 7;
    const int tid = threadIdx.x;
    const int base = b * NTOK;
    const int cnt = min(counts[blk], CAP);
    const int lbase = blk * CAP;
    const float m = mblk[blk], ws = wscale[blk];

    float4 acc = {0.f, 0.f, 0.f, 0.f};
    for (int i = 0; i < cnt; ++i) {
        int n = lists[lbase + i];
        float w = __expf(gate[base + n] - m);
        float4 xv = *reinterpret_cast<const float4*>(&x[(size_t)(base + n) * HDIM + tid * 4]);
        acc.x += w * xv.x; acc.y += w * xv.y; acc.z += w * xv.z; acc.w += w * xv.w;
    }
    short o[4] = {f2bf(acc.x * ws), f2bf(acc.y * ws), f2bf(acc.z * ws), f2bf(acc.w * ws)};
    *reinterpret_cast<int2*>(&pooled[(size_t)blk * HDIM + tid * 4]) =
        *reinterpret_cast<const int2*>(o);
}

// ---------------------------------------------------------------------------
// GEMM2: y = pooled @ Wp + bp. 1024^3. 64x64 tiles, 4 waves, dbuf + gll,
// counted-vmcnt schedule.
// ---------------------------------------------------------------------------
__global__ __launch_bounds__(256) void k_gemm2(
    const bf16s* __restrict__ pooled, const bf16s* __restrict__ wpt,
    const float* __restrict__ bp, float* __restrict__ y)
{
    __shared__ alignas(16) bf16s As[2][64 * 32];
    __shared__ alignas(16) bf16s Bs[2][64 * 32];
    const int tid = threadIdx.x;
    const int lane = tid & 63;
    const int wv = tid >> 6;
    const int wr = wv >> 1, wc = wv & 1;
    const int row0 = (blockIdx.x >> 4) * 64, col0 = (blockIdx.x & 15) * 64;
    const int c0 = lane & 15, khalf = lane >> 4;

    const int sr = wv * 16 + (lane >> 2);
    const int sj = (lane & 3) ^ ((sr >> 1) & 3);
    const int sdst = (wv * 16) * 32 + lane * 8;
    const bf16s* srcA = &pooled[(size_t)(row0 + sr) * 1024 + sj * 8];
    const bf16s* srcB = &wpt[(size_t)(col0 + sr) * 1024 + sj * 8];

    f32x4 acc[2][2] = {};

    gload_lds16(srcA, &As[0][sdst]);
    gload_lds16(srcB, &Bs[0][sdst]);

    for (int t = 0; t < 32; ++t) {
        const int cur = t & 1;
        if (t < 31) {
            gload_lds16(srcA + (t + 1) * 32, &As[cur ^ 1][sdst]);
            gload_lds16(srcB + (t + 1) * 32, &Bs[cur ^ 1][sdst]);
            asm volatile("s_waitcnt vmcnt(2)" ::: "memory");
        } else {
            asm volatile("s_waitcnt vmcnt(0)" ::: "memory");
        }
        __builtin_amdgcn_s_barrier();
        __builtin_amdgcn_sched_barrier(0);
        #pragma unroll
        for (int mf = 0; mf < 2; ++mf) {
            int ra = wr * 32 + mf * 16 + c0;
            short8 av = *reinterpret_cast<const short8*>(
                &As[cur][ra * 32 + ((khalf ^ ((ra >> 1) & 3)) * 8)]);
            #pragma unroll
            for (int nf = 0; nf < 2; ++nf) {
                int rb = wc * 32 + nf * 16 + c0;
                short8 bv = *reinterpret_cast<const short8*>(
                    &Bs[cur][rb * 32 + ((khalf ^ ((rb >> 1) & 3)) * 8)]);
                acc[mf][nf] = __builtin_amdgcn_mfma_f32_16x16x32_bf16(av, bv, acc[mf][nf], 0, 0, 0);
            }
        }
        asm volatile("s_waitcnt lgkmcnt(0)" ::: "memory");
        __builtin_amdgcn_sched_barrier(0);
        __builtin_amdgcn_s_barrier();
    }
    #pragma unroll
    for (int mf = 0; mf < 2; ++mf)
        #pragma unroll
        for (int nf = 0; nf < 2; ++nf)
            #pragma unroll
            for (int reg = 0; reg < 4; ++reg) {
                int grow = row0 + wr * 32 + mf * 16 + khalf * 4 + reg;
                int gcol = col0 + wc * 32 + nf * 16 + c0;
                y[(size_t)grow * 1024 + gcol] = acc[mf][nf][reg] + bp[gcol];
            }
}

// ---------------------------------------------------------------------------
// LayerNorm + ELU + present-mask.
// ---------------------------------------------------------------------------
__global__ void k_lnelu(const float* __restrict__ y, const float* __restrict__ ln_g,
                        const float* __restrict__ ln_b, const int* __restrict__ counts,
                        float* __restrict__ outp)
{
    const int row = blockIdx.x;
    const int k = row & 127;
    const int tid = threadIdx.x;

    float4 v = *reinterpret_cast<const float4*>(&y[(size_t)row * 1024 + tid * 4]);
    float s = v.x + v.y + v.z + v.w;
    float ss = v.x * v.x + v.y * v.y + v.z * v.z + v.w * v.w;
    #pragma unroll
    for (int off = 32; off; off >>= 1) { s += __shfl_xor(s, off); ss += __shfl_xor(ss, off); }

    __shared__ float sbuf[4], ssbuf[4];
    int wv = tid >> 6;
    if ((tid & 63) == 0) { sbuf[wv] = s; ssbuf[wv] = ss; }
    __syncthreads();
    s = sbuf[0] + sbuf[1] + sbuf[2] + sbuf[3];
    ss = ssbuf[0] + ssbuf[1] + ssbuf[2] + ssbuf[3];

    float mu = s * (1.f / 1024.f);
    float var = ss * (1.f / 1024.f) - mu * mu;
    float rstd = rsqrtf(var + 1e-5f);

    bool pres = false;
    #pragma unroll
    for (int bb = 0; bb < 8; ++bb) pres = pres || (counts[bb * NBLK + k] > 0);

    float4 g4 = *reinterpret_cast<const float4*>(&ln_g[tid * 4]);
    float4 b4 = *reinterpret_cast<const float4*>(&ln_b[tid * 4]);
    float vals[4] = {v.x, v.y, v.z, v.w};
    float gs[4] = {g4.x, g4.y, g4.z, g4.w};
    float bs[4] = {b4.x, b4.y, b4.z, b4.w};
    float4 o;
    float* op = &o.x;
    #pragma unroll
    for (int j = 0; j < 4; ++j) {
        float t = (vals[j] - mu) * rstd * gs[j] + bs[j];
        t = (t > 0.f) ? t : expm1f(t);
        op[j] = pres ? t : 0.f;
    }
    *reinterpret_cast<float4*>(&outp[(size_t)row * 1024 + tid * 4]) = o;
}

// ---------------------------------------------------------------------------
extern "C" void kernel_launch(void* const* d_in, const int* in_sizes, int n_in,
                              void* d_out, int out_size, void* d_ws, size_t ws_size,
                              hipStream_t stream)
{
    const float* x      = (const float*)d_in[0];
    const int*   ct     = (const int*)d_in[1];
    const int*   bids   = (const int*)d_in[2];
    const unsigned char* pad = (const unsigned char*)d_in[3];
    const float* W1     = (const float*)d_in[4];
    const float* b1     = (const float*)d_in[5];
    const float* W2     = (const float*)d_in[6];
    const float* b2     = (const float*)d_in[7];
    const float* ct_emb = (const float*)d_in[8];
    const float* Wp     = (const float*)d_in[9];
    const float* bp     = (const float*)d_in[10];
    const float* ln_g   = (const float*)d_in[11];
    const float* ln_b   = (const float*)d_in[12];
    float* outF = (float*)d_out;

    char* ws = (char*)d_ws;
    bf16s* w1t    = (bf16s*)(ws + 0);          //  1,048,576
    bf16s* wpt    = (bf16s*)(ws + 1048576);    //  2,097,152 -> 3,145,728
    float* gate   = (float*)(ws + 3145728);    //    131,072 -> 3,276,800
    float* part   = (float*)(ws + 3276800);    //    524,288 -> 3,801,088 (2 used)
    float* mblk   = (float*)(ws + 3801088);
    float* wscal  = (float*)(ws + 3805184);
    int*   counts = (int*)  (ws + 3809280);
    int*   lists  = (int*)  (ws + 3813376);    //  1,048,576 -> 4,861,952
    bf16s* pooled = (bf16s*)(ws + 4861952);    //  2,097,152 -> 6,959,104
    float* ybuf   = (float*)(ws + 6959104);    //  4,194,304 -> 11,153,408

    k_tcvt2<<<dim3(16, 24), 256, 0, stream>>>(W1, Wp, w1t, wpt);
    k_gemmv<<<512, 256, 0, stream>>>(x, w1t, b1, W2, part);
    k_blocks<<<1024, 64, 0, stream>>>(bids, pad, part, b2, gate, ct, ct_emb,
                                      counts, mblk, wscal, lists,
                                      outF + (size_t)8 * NBLK * HDIM);
    k_pool<<<1024, 256, 0, stream>>>(x, gate, lists, counts, mblk, wscal, pooled);
    k_gemm2<<<256, 256, 0, stream>>>(pooled, wpt, bp, ybuf);
    k_lnelu<<<1024, 256, 0, stream>>>(ybuf, ln_g, ln_b, counts, outF);
}